// Round 9
// baseline (194.207 us; speedup 1.0000x reference)
//
#include <hip/hip_runtime.h>
#include <hip/hip_bf16.h>
#include <math.h>

#define B_   2
#define N_   2048
#define E_   1024
#define H_   16
#define D_   64
#define E3_  3072
#define M_   (B_ * N_)   // 4096

// log2(e)/8 folded into Q so softmax inner loop is a bare exp2
#define QSCALE 0.18033688011112042f

using short8  = __attribute__((ext_vector_type(8))) short;
using short4v = __attribute__((ext_vector_type(4))) short;
using f32x4   = __attribute__((ext_vector_type(4))) float;
using uint2v  = __attribute__((ext_vector_type(2))) unsigned int;
using uint4v  = __attribute__((ext_vector_type(4))) unsigned int;

#define MFMA16(a, b, c)    __builtin_amdgcn_mfma_f32_16x16x32_bf16((a), (b), (c), 0, 0, 0)

__device__ __forceinline__ unsigned short f2bf(float f) {
    __hip_bfloat16 h = __float2bfloat16(f);
    return __builtin_bit_cast(unsigned short, h);
}

__device__ __forceinline__ float fast_exp2(float x) {
#if __has_builtin(__builtin_amdgcn_exp2f)
    return __builtin_amdgcn_exp2f(x);
#else
    return exp2f(x);
#endif
}

// pack two floats to a bf16x2 dword.  gfx950 has v_cvt_pk_bf16_f32 (1 op,
// RNE); fallback = round-half-up bit trick (3 ops).
__device__ __forceinline__ unsigned int pack_bf16_2(float lo, float hi) {
#if __has_builtin(__builtin_amdgcn_cvt_pk_bf16_f32)
    auto pk = __builtin_amdgcn_cvt_pk_bf16_f32(lo, hi);
    return *(const unsigned int*)&pk;
#else
    unsigned int ulo = __builtin_bit_cast(unsigned int, lo) + 0x8000u;
    unsigned int uhi = __builtin_bit_cast(unsigned int, hi) + 0x8000u;
#if __has_builtin(__builtin_amdgcn_perm)
    return __builtin_amdgcn_perm(uhi, ulo, 0x07060302u);
#else
    return (uhi & 0xFFFF0000u) | (ulo >> 16);
#endif
#endif
}

// async global->LDS, 16B per lane
__device__ __forceinline__ void gl16(const void* g, void* l) {
    __builtin_amdgcn_global_load_lds(
        (__attribute__((address_space(1))) const void*)g,
        (__attribute__((address_space(3))) void*)l, 16, 0, 0);
}

// ---------------------------------------------------------------------------
// Kernel 0: fp32->bf16: x->xb; w_qkv row-permuted (slot s = c*1024+h*64+d) ->
// wqp; w_proj->wpb.  Block 4096: permuted (+Q-prescaled) bias -> bias_perm.
// ---------------------------------------------------------------------------
__global__ __launch_bounds__(256) void convert_kernel(
    const float* __restrict__ x, const float* __restrict__ wq,
    const float* __restrict__ wp, const float* __restrict__ b_qkv,
    unsigned short* __restrict__ xb, unsigned short* __restrict__ wqp,
    unsigned short* __restrict__ wpb, float* __restrict__ bias_perm)
{
    if (blockIdx.x == 4096) {
        for (int q = threadIdx.x; q < E3_; q += 256) {
            const int c = q >> 10, rem = q & 1023;
            const int h = rem >> 6, d = rem & 63;
            float v = b_qkv[h * 192 + d * 3 + c];
            if (c == 0) v *= QSCALE;
            bias_perm[q] = v;
        }
        return;
    }
    const int o = (blockIdx.x * 256 + threadIdx.x) * 8;
    const float* src;
    unsigned short* dst;
    if (o < 4194304) {                     // x: 4M
        src = x + o; dst = xb + o;
    } else if (o < 7340032) {              // w_qkv permuted: 3M
        const int oo = o - 4194304;
        const int s = oo >> 10, k = oo & 1023;
        const int c = s >> 10, rem = s & 1023;
        const int h = rem >> 6, d = rem & 63;
        src = wq + (size_t)(h * 192 + d * 3 + c) * E_ + k;
        dst = wqp + oo;
    } else {                               // w_proj: 1M
        const int oo = o - 7340032;
        src = wp + oo; dst = wpb + oo;
    }
    float4 a = *(const float4*)src;
    float4 b = *(const float4*)(src + 4);
    uint2v p0, p1;
    p0.x = pack_bf16_2(a.x, a.y); p0.y = pack_bf16_2(a.z, a.w);
    p1.x = pack_bf16_2(b.x, b.y); p1.y = pack_bf16_2(b.z, b.w);
    *(uint2v*)dst = p0;
    *(uint2v*)(dst + 4) = p1;
}

#define GEMM_PROLOG                                                          \
    const int t    = threadIdx.x;                                            \
    const int wv   = t >> 6, lane = t & 63;                                  \
    const int quad = lane >> 4, l15 = lane & 15;                             \
    const int wr   = wv & 1, wc = wv >> 1;                                   \
    f32x4 acc[4][4];                                                         \
    _Pragma("unroll")                                                        \
    for (int i = 0; i < 4; ++i)                                              \
        _Pragma("unroll")                                                    \
        for (int j = 0; j < 4; ++j) acc[i][j] = (f32x4){0.f, 0.f, 0.f, 0.f};

// ---------------------------------------------------------------------------
// Kernel 1: merged qkv GEMM over all 3072 output slots (grid 24 x 32).
// 128x128 tile, BK=32, 4 waves (2x2), global_load_lds(16B), XOR-swizzled
// LDS, 2-buffer ping-pong + __syncthreads (R6-verified).
// r13: XCD-aware block swizzle (T1), 768 = 8*96 bijective.
// r14: V-branch stores VT key-paired (slot gi*8+hi*4+j) -> attn PV at K=32.
// r17: staging addresses hoisted to per-lane base pointers; fragment LDS
// offsets precomputed.
// ---------------------------------------------------------------------------
__global__ __launch_bounds__(256) void qkv_kernel(
    const unsigned short* __restrict__ A, const unsigned short* __restrict__ Bm,
    const float* __restrict__ bias_perm,
    unsigned short* __restrict__ Q, unsigned short* __restrict__ K,
    unsigned short* __restrict__ VT)
{
    __shared__ __attribute__((aligned(16))) unsigned short As[2][128 * 32];
    __shared__ __attribute__((aligned(16))) unsigned short Bs[2][128 * 32];
    GEMM_PROLOG
    // XCD swizzle: HW round-robins original linear id across 8 XCDs.
    const int lid = blockIdx.x + 24 * blockIdx.y;        // 0..767
    const int swz = (lid & 7) * 96 + (lid >> 3);         // bijective (768=8*96)
    const int bx  = swz % 24, by = swz / 24;
    const int bm = by * 128;   // token rows
    const int bn = bx * 128;   // s slots
    const int c  = bn >> 10;   // 0=Q,1=K,2=V (uniform per block)

    // --- r17 hoisted staging bases (identical address algebra to r13) ---
    const int chunk0 = wv * 128 + lane;
    const int row0   = chunk0 >> 2;
    const int g0     = ((chunk0 & 3) ^ ((row0 >> 1) & 3)) * 8;
    const int chunk1 = chunk0 + 64;
    const int row1   = chunk1 >> 2;
    const int g1     = ((chunk1 & 3) ^ ((row1 >> 1) & 3)) * 8;
    const unsigned short* aS0 = A  + (size_t)(bm + row0) * E_ + g0;
    const unsigned short* aS1 = A  + (size_t)(bm + row1) * E_ + g1;
    const unsigned short* bS0 = Bm + (size_t)(bn + row0) * E_ + g0;
    const unsigned short* bS1 = Bm + (size_t)(bn + row1) * E_ + g1;
    const int ldsOff0 = wv * 1024;        // shorts: (wv*128+ 0)*8
    const int ldsOff1 = wv * 1024 + 512;  // shorts: (wv*128+64)*8

#define QKV_STAGE(buf, k0)                                                   \
    {                                                                        \
        gl16(aS0 + (k0), &As[buf][ldsOff0]);                                 \
        gl16(bS0 + (k0), &Bs[buf][ldsOff0]);                                 \
        gl16(aS1 + (k0), &As[buf][ldsOff1]);                                 \
        gl16(bS1 + (k0), &Bs[buf][ldsOff1]);                                 \
    }

    // --- r17 hoisted fragment offsets (loop-invariant) ---
    const int sw = (l15 >> 1) & 3;
    int offM[4], offN[4];
#pragma unroll
    for (int i = 0; i < 4; ++i) {
        offM[i] = (wr * 64 + i * 16 + l15) * 32 + ((quad ^ sw) * 8);
        offN[i] = (wc * 64 + i * 16 + l15) * 32 + ((quad ^ sw) * 8);
    }

    QKV_STAGE(0, 0);
    if (c < 2) {
        for (int it = 0; it < 32; ++it) {
            const int cur = it & 1;
            __syncthreads();
            if (it < 31) QKV_STAGE(cur ^ 1, (it + 1) * 32);
            short8 af[4], bf[4];
#pragma unroll
            for (int i = 0; i < 4; ++i) {
                af[i] = *(const short8*)&Bs[cur][offM[i]];   // m = s slots
                bf[i] = *(const short8*)&As[cur][offN[i]];   // n = tokens
            }
#pragma unroll
            for (int i = 0; i < 4; ++i)
#pragma unroll
                for (int j = 0; j < 4; ++j)
                    acc[i][j] = MFMA16(af[i], bf[j], acc[i][j]);  // D[m=s][n=tok]
        }
        const float scale = (c == 0) ? QSCALE : 1.0f;
        unsigned short* dst0 = (c == 0) ? Q : K;
#pragma unroll
        for (int i = 0; i < 4; ++i) {
            const int s0 = bn + wr * 64 + i * 16 + quad * 4;
            const int h  = (s0 >> 6) & 15;
            const int d0 = s0 & 63;
            const float4 bq = *(const float4*)(bias_perm + s0);
#pragma unroll
            for (int j = 0; j < 4; ++j) {
                const int row = bm + wc * 64 + j * 16 + l15;
                const int b   = row >> 11, n = row & (N_ - 1);
                const float v0 = fmaf(acc[i][j][0], scale, bq.x);
                const float v1 = fmaf(acc[i][j][1], scale, bq.y);
                const float v2 = fmaf(acc[i][j][2], scale, bq.z);
                const float v3 = fmaf(acc[i][j][3], scale, bq.w);
                uint2v pk;
                pk.x = pack_bf16_2(v0, v1);
                pk.y = pack_bf16_2(v2, v3);
                *(uint2v*)(dst0 + (((size_t)b * H_ + h) * N_ + n) * D_ + d0) = pk;
            }
        }
    } else {
        for (int it = 0; it < 32; ++it) {
            const int cur = it & 1;
            __syncthreads();
            if (it < 31) QKV_STAGE(cur ^ 1, (it + 1) * 32);
            short8 af[4], bf[4];
#pragma unroll
            for (int i = 0; i < 4; ++i) {
                af[i] = *(const short8*)&As[cur][offM[i]];   // m = tokens
                bf[i] = *(const short8*)&Bs[cur][offN[i]];   // n = s slots
            }
#pragma unroll
            for (int i = 0; i < 4; ++i)
#pragma unroll
                for (int j = 0; j < 4; ++j)
                    acc[i][j] = MFMA16(af[i], bf[j], acc[i][j]);  // D[m=tok][n=s]
        }
#pragma unroll
        for (int j = 0; j < 4; ++j) {
            const int s = bn + wc * 64 + j * 16 + l15;
            const int h = (s >> 6) & 15, d = s & 63;
            const float bv = bias_perm[s];
#pragma unroll
            for (int i = 0; i < 4; ++i) {
                const int row0v = bm + wr * 64 + i * 16 + quad * 4;
                const int b     = row0v >> 11, n0 = row0v & (N_ - 1);
                // r14 key-pair permutation (bijective on 4-aligned groups):
                // np = (n0 & ~31) | gi*8 + hi*4, gi = (n0>>2)&3, hi = (n0>>4)&1
                const int np = (n0 & ~31) | ((((n0 >> 2) & 3) << 3) + (((n0 >> 4) & 1) << 2));
                uint2v pk;
                pk.x = pack_bf16_2(acc[i][j][0] + bv, acc[i][j][1] + bv);
                pk.y = pack_bf16_2(acc[i][j][2] + bv, acc[i][j][3] + bv);
                *(uint2v*)(VT + (((size_t)b * H_ + h) * D_ + d) * N_ + np) = pk;
            }
        }
    }
#undef QKV_STAGE
}

// ---------------------------------------------------------------------------
// Kernel 2: flash attention, 2x2 hybrid partition (r10 sync structure).
// Wave (wq,wk): q-rows [wq*32,+32), keys [wk*32,+32).  S^T = K_own.Q_own;
// P stays in registers as the A-operand.
// r15: PV and l = P.1 at K=32 (16x16x32 A/B k-map is k = quad*8+e; the r14
// VT slot order kappa equals concat(pa[kb0], pa[kb1])).
// r17: staging bases + inner LDS offsets hoisted out of the kt loop.
// r18: __launch_bounds__(256, 4) — SINGLE-VARIABLE experiment.  Grid is
// 1024 = 4*256: at 3 blocks/CU the 4th generation (256 blocks) runs at 1/3
// occupancy (~25% of attn wall).  4 blocks/CU = one full generation, zero
// tail.  LDS 4*33280 = 133120 <= 163840; VGPR 52 <= 128.  (r11/r12's
// (256,4) replay failures were confounded: r11 = wrong K=32 slot map
// [proven by r15], r12 = simultaneous partition restructure.  This is the
// minimal test.  If replay diverges -> bounds itself is the poison,
// permanent revert to (256,3).)
// PV: 8 MFMAs/kt, lsum: 2, QK: 8 -> 18 passes/kt.
// LDS: 32 KB tile pool (dbuf K+V) + 512 B lsum.
// ---------------------------------------------------------------------------
__global__ __launch_bounds__(256, 4) void attn_kernel(
    const unsigned short* __restrict__ Q, const unsigned short* __restrict__ K,
    const unsigned short* __restrict__ VT, unsigned short* __restrict__ CTX)
{
    __shared__ __attribute__((aligned(16))) unsigned short pool[16384]; // Ks[2]|Vs[2]
    __shared__ float lsumBuf[2][64];   // [wk][q]

    const int t    = threadIdx.x;
    const int wv   = t >> 6, lane = t & 63;
    const int quad = lane >> 4, l15 = lane & 15;
    const int wq   = wv & 1, wk = wv >> 1;
    const int qt   = blockIdx.x & 31;   // N/64 q-tiles
    const int bh   = blockIdx.x >> 5;

    const unsigned short* Kp = K + (size_t)bh * N_ * D_;
    const unsigned short* Vp = VT + (size_t)bh * D_ * N_;

    // Q B-frags for this wave's 2 q-subtiles (global subtiles wq*2+s)
    short8 qf[2][2];
#pragma unroll
    for (int s = 0; s < 2; ++s) {
        const unsigned short* Qp =
            Q + ((size_t)bh * N_ + qt * 64 + (wq * 2 + s) * 16 + l15) * D_;
        qf[s][0] = *(const short8*)(Qp + quad * 8);
        qf[s][1] = *(const short8*)(Qp + 32 + quad * 8);
    }

    // --- r17 hoisted staging bases (identical algebra to r10 macro) ---
    const int cch0 = (wv * 2) * 64 + lane;
    const int srow0 = cch0 >> 3;
    const int sgc0  = ((cch0 & 7) ^ (srow0 & 7)) * 8;
    const int cch1 = cch0 + 64;
    const int srow1 = cch1 >> 3;
    const int sgc1  = ((cch1 & 7) ^ (srow1 & 7)) * 8;
    const unsigned short* kS0 = Kp + (size_t)srow0 * D_ + sgc0;
    const unsigned short* kS1 = Kp + (size_t)srow1 * D_ + sgc1;
    const unsigned short* vS0 = Vp + (size_t)srow0 * N_ + sgc0;
    const unsigned short* vS1 = Vp + (size_t)srow1 * N_ + sgc1;
    const int aOff0 = (wv * 2) * 512, aOff1 = aOff0 + 512;

#define ATTN_STAGE(buf, kt)                                                  \
    {                                                                        \
        gl16(kS0 + (kt) * (64 * D_), &pool[(buf) * 4096 + aOff0]);           \
        gl16(vS0 + (kt) * 64,        &pool[8192 + (buf) * 4096 + aOff0]);    \
        gl16(kS1 + (kt) * (64 * D_), &pool[(buf) * 4096 + aOff1]);           \
        gl16(vS1 + (kt) * 64,        &pool[8192 + (buf) * 4096 + aOff1]);    \
    }

    // --- r17 hoisted inner LDS read offsets (loop-invariant) ---
    const int koff0 = (quad ^ (l15 & 7)) * 8;
    const int koff1 = ((4 + quad) ^ (l15 & 7)) * 8;
    const int vs128 = ((wk * 4 + quad) ^ (l15 & 7)) * 8;
    int kOff0[2], kOff1[2], vOff[4];
#pragma unroll
    for (int kb = 0; kb < 2; ++kb) {
        const int krow = (wk * 32 + kb * 16 + l15) * 64;
        kOff0[kb] = krow + koff0;
        kOff1[kb] = krow + koff1;
    }
#pragma unroll
    for (int nt = 0; nt < 4; ++nt)
        vOff[nt] = (nt * 16 + l15) * 64 + vs128;

    // bf16 1.0 x8 for the l = P.1 MFMA (K=32)
    short8 ones8;
#pragma unroll
    for (int i = 0; i < 8; ++i) ones8[i] = (short)0x3F80;

    f32x4 O[2][4];   // [q-subtile][nt] partial over this wave's 32 keys
#pragma unroll
    for (int s = 0; s < 2; ++s)
#pragma unroll
        for (int nt = 0; nt < 4; ++nt) O[s][nt] = (f32x4){0.f, 0.f, 0.f, 0.f};
    f32x4 Lacc[2] = {{0.f, 0.f, 0.f, 0.f}, {0.f, 0.f, 0.f, 0.f}};

    ATTN_STAGE(0, 0);

    for (int kt = 0; kt < 32; ++kt) {
        const int cur = kt & 1;
        __syncthreads();
        if (kt < 31) ATTN_STAGE(cur ^ 1, kt + 1);

        const unsigned short* Kc = pool + cur * 4096;
        const unsigned short* Vc = pool + 8192 + cur * 4096;

        // S^T per key-group kb (16 keys) x q-subtile s
        f32x4 st[2][2];
#pragma unroll
        for (int kb = 0; kb < 2; ++kb) {
            const short8 kf0 = *(const short8*)&Kc[kOff0[kb]];
            const short8 kf1 = *(const short8*)&Kc[kOff1[kb]];
#pragma unroll
            for (int s = 0; s < 2; ++s) {
                st[kb][s] = (f32x4){0.f, 0.f, 0.f, 0.f};
                st[kb][s] = MFMA16(kf0, qf[s][0], st[kb][s]);
                st[kb][s] = MFMA16(kf1, qf[s][1], st[kb][s]);
            }
        }

        // softmax numerator: p = exp2(s), packed straight into the K=32
        // A-operand slot order: e<4 = kb0 keys quad*4+e, e>=4 = kb1 keys
        // 16+quad*4+(e-4)  (= r14 VT slot order kappa).
        short8 pa8[2];
#pragma unroll
        for (int s = 0; s < 2; ++s) {
            uint4v u;
            u.x = pack_bf16_2(fast_exp2(st[0][s][0]), fast_exp2(st[0][s][1]));
            u.y = pack_bf16_2(fast_exp2(st[0][s][2]), fast_exp2(st[0][s][3]));
            u.z = pack_bf16_2(fast_exp2(st[1][s][0]), fast_exp2(st[1][s][1]));
            u.w = pack_bf16_2(fast_exp2(st[1][s][2]), fast_exp2(st[1][s][3]));
            pa8[s] = __builtin_bit_cast(short8, u);
        }

        // l partials via MFMA (K=32): Lacc[s] += P[s] . 1
#pragma unroll
        for (int s = 0; s < 2; ++s)
            Lacc[s] = MFMA16(pa8[s], ones8, Lacc[s]);

        // PV (K=32): O[s][nt] += P[s] . V(all 32 keys of this wave);
        // one b128 read + one MFMA per (s,nt)
#pragma unroll
        for (int nt = 0; nt < 4; ++nt) {
            const short8 v8 = *(const short8*)&Vc[vOff[nt]];
#pragma unroll
            for (int s = 0; s < 2; ++s)
                O[s][nt] = MFMA16(pa8[s], v8, O[s][nt]);
        }
    }
#undef ATTN_STAGE

    // Lacc D-layout: row q_local = quad*4+g, all 16 cols identical -> lane
    // l15==0 of each quad publishes its 4 q rows.
    if (l15 == 0) {
#pragma unroll
        for (int s = 0; s < 2; ++s)
#pragma unroll
            for (int g = 0; g < 4; ++g)
                lsumBuf[wk][wq * 32 + s * 16 + quad * 4 + g] = Lacc[s][g];
    }
    __syncthreads();   // tile reads done (pool reusable) + lsumBuf visible

    // O D-layout: q = quad*4+g (row), d = nt*16 + l15 (col)
    float* red = (float*)pool;   // 8192 floats; [wq][qsub 0..31][d 0..63]
    if (wk == 1) {
#pragma unroll
        for (int s = 0; s < 2; ++s)
#pragma unroll
            for (int nt = 0; nt < 4; ++nt)
#pragma unroll
                for (int g = 0; g < 4; ++g)
                    red[wq * 2048 + (s * 16 + quad * 4 + g) * 64 + nt * 16 + l15] =
                        O[s][nt][g];
    }
    __syncthreads();

    if (wk == 0) {
        const int b = bh >> 4, h = bh & 15;
#pragma unroll
        for (int s = 0; s < 2; ++s) {
            float inv[4];
#pragma unroll
            for (int g = 0; g < 4; ++g) {
                const int q = wq * 32 + s * 16 + quad * 4 + g;
                inv[g] = 1.0f / (lsumBuf[0][q] + lsumBuf[1][q]);
            }
#pragma unroll
            for (int nt = 0; nt < 4; ++nt) {
#pragma unroll
                for (int g = 0; g < 4; ++g) {
                    const float o = O[s][nt][g] +
                        red[wq * 2048 + (s * 16 + quad * 4 + g) * 64 + nt * 16 + l15];
                    const int qrow = qt * 64 + wq * 32 + s * 16 + quad * 4 + g;
                    CTX[((size_t)b * N_ + qrow) * E_ + h * D_ + nt * 16 + l15] =
                        f2bf(o * inv[g]);
                }
            }
        }
    }
}

// ---------------------------------------------------------------------------
// Kernel 3: out = ctx @ w_proj^T + b_proj.  128(M) x 64(N) tiles -> 512
// blocks = 2/CU.  C^T orientation -> float4 stores.
// r13: XCD-aware block swizzle (T1), 512 = 8*64 bijective.
// r17: staging bases + fragment offsets hoisted.
// ---------------------------------------------------------------------------
__global__ __launch_bounds__(256) void proj_kernel(
    const unsigned short* __restrict__ A, const unsigned short* __restrict__ Bm,
    const float* __restrict__ bias, float* __restrict__ out)
{
    __shared__ __attribute__((aligned(16))) unsigned short As[2][128 * 32];
    __shared__ __attribute__((aligned(16))) unsigned short Bs[2][64 * 32];
    const int t    = threadIdx.x;
    const int wv   = t >> 6, lane = t & 63;
    const int quad = lane >> 4, l15 = lane & 15;
    const int wr   = wv & 1, wc = wv >> 1;
    const int lid  = blockIdx.x + 16 * blockIdx.y;       // 0..511
    const int swz  = (lid & 7) * 64 + (lid >> 3);        // bijective (512=8*64)
    const int bx   = swz & 15, by = swz >> 4;
    const int bm   = by * 128;   // ctx rows
    const int bn   = bx * 64;    // out cols

    f32x4 acc[2][4];
#pragma unroll
    for (int i = 0; i < 2; ++i)
#pragma unroll
        for (int j = 0; j < 4; ++j) acc[i][j] = (f32x4){0.f, 0.f, 0.f, 0.f};

    // --- r17 hoisted staging bases ---
    const int pc0 = wv * 128 + lane, pr0 = pc0 >> 2;
    const int pg0 = ((pc0 & 3) ^ ((pr0 >> 1) & 3)) * 8;
    const int pc1 = pc0 + 64, pr1 = pc1 >> 2;
    const int pg1 = ((pc1 & 3) ^ ((pr1 >> 1) & 3)) * 8;
    const int pcB = wv * 64 + lane, prB = pcB >> 2;
    const int pgB = ((pcB & 3) ^ ((prB >> 1) & 3)) * 8;
    const unsigned short* aS0 = A  + (size_t)(bm + pr0) * E_ + pg0;
    const unsigned short* aS1 = A  + (size_t)(bm + pr1) * E_ + pg1;
    const unsigned short* bS  = Bm + (size_t)(bn + prB) * E_ + pgB;
    const int ldsA0 = wv * 1024, ldsA1 = wv * 1024 + 512, ldsB0 = wv * 512;

#define PROJ_STAGE(buf, k0)                                                  \
    {                                                                        \
        gl16(aS0 + (k0), &As[buf][ldsA0]);                                   \
        gl16(aS1 + (k0), &As[buf][ldsA1]);                                   \
        gl16(bS  + (k0), &Bs[buf][ldsB0]);                                   \
    }

    // --- r17 hoisted fragment offsets ---
    const int sw = (l15 >> 1) & 3;
    int offPM[2], offPN[4];
#pragma unroll
    for (int i = 0; i < 2; ++i)
        offPM[i] = (wr * 32 + i * 16 + l15) * 32 + ((quad ^ sw) * 8);
#pragma unroll
    for (int j = 0; j < 4; ++j)
        offPN[j] = (wc * 64 + j * 16 + l15) * 32 + ((quad ^ sw) * 8);

    PROJ_STAGE(0, 0);
    for (int it = 0; it < 32; ++it) {
        const int cur = it & 1;
        __syncthreads();
        if (it < 31) PROJ_STAGE(cur ^ 1, (it + 1) * 32);
        short8 af[2], bf[4];
#pragma unroll
        for (int i = 0; i < 2; ++i)
            af[i] = *(const short8*)&Bs[cur][offPM[i]];
#pragma unroll
        for (int j = 0; j < 4; ++j)
            bf[j] = *(const short8*)&As[cur][offPN[j]];
#pragma unroll
        for (int i = 0; i < 2; ++i)
#pragma unroll
            for (int j = 0; j < 4; ++j)
                acc[i][j] = MFMA16(af[i], bf[j], acc[i][j]);   // D[m=col][n=row]
    }
#undef PROJ_STAGE

#pragma unroll
    for (int i = 0; i < 2; ++i) {
        const int col0 = bn + wr * 32 + i * 16 + quad * 4;
        const float4 bp = *(const float4*)(bias + col0);
#pragma unroll
        for (int j = 0; j < 4; ++j) {
            const int row = bm + wc * 64 + j * 16 + l15;
            float4 o;
            o.x = acc[i][j][0] + bp.x;
            o.y = acc[i][j][1] + bp.y;
            o.z = acc[i][j][2] + bp.z;
            o.w = acc[i][j][3] + bp.w;
            *(float4*)(out + (size_t)row * E_ + col0) = o;
        }
    }
}

// ---------------------------------------------------------------------------
extern "C" void kernel_launch(void* const* d_in, const int* in_sizes, int n_in,
                              void* d_out, int out_size, void* d_ws, size_t ws_size,
                              hipStream_t stream)
{
    const float* x      = (const float*)d_in[0];
    const float* w_qkv  = (const float*)d_in[1];
    const float* b_qkv  = (const float*)d_in[2];
    const float* w_proj = (const float*)d_in[3];
    const float* b_proj = (const float*)d_in[4];
    float* out = (float*)d_out;

    // ws (bf16 elems): xb 4M | wqp 3M | wpb 1M | Q 4M | K 4M | VT 4M | CTX 4M
    // then bias_perm (3072 fp32)
    unsigned short* xb  = (unsigned short*)d_ws;
    unsigned short* wqp = xb  + 4194304;
    unsigned short* wpb = wqp + 3145728;
    unsigned short* Q   = wpb + 1048576;
    unsigned short* K   = Q   + 4194304;
    unsigned short* VT  = K   + 4194304;
    unsigned short* CTX = VT  + 4194304;
    float* bias_perm    = (float*)(CTX + 4194304);

    dim3 blk(256);
    convert_kernel<<<dim3(4097), blk, 0, stream>>>(
        x, w_qkv, w_proj, b_qkv, xb, wqp, wpb, bias_perm);

    qkv_kernel<<<dim3(24, 32), blk, 0, stream>>>(xb, wqp, bias_perm, Q, K, VT);

    attn_kernel<<<dim3(B_ * H_ * (N_ / 64)), blk, 0, stream>>>(Q, K, VT, CTX);

    proj_kernel<<<dim3(16, 32), blk, 0, stream>>>(CTX, wpb, b_proj, out);
}

// Round 10
// 191.573 us; speedup vs baseline: 1.0138x; 1.0138x over previous
//
#include <hip/hip_runtime.h>
#include <hip/hip_bf16.h>
#include <math.h>

#define B_   2
#define N_   2048
#define E_   1024
#define H_   16
#define D_   64
#define E3_  3072
#define M_   (B_ * N_)   // 4096

// log2(e)/8 folded into Q so softmax inner loop is a bare exp2
#define QSCALE 0.18033688011112042f

using short8  = __attribute__((ext_vector_type(8))) short;
using short4v = __attribute__((ext_vector_type(4))) short;
using f32x4   = __attribute__((ext_vector_type(4))) float;
using uint2v  = __attribute__((ext_vector_type(2))) unsigned int;
using uint4v  = __attribute__((ext_vector_type(4))) unsigned int;

#define MFMA16(a, b, c)    __builtin_amdgcn_mfma_f32_16x16x32_bf16((a), (b), (c), 0, 0, 0)

__device__ __forceinline__ unsigned short f2bf(float f) {
    __hip_bfloat16 h = __float2bfloat16(f);
    return __builtin_bit_cast(unsigned short, h);
}

__device__ __forceinline__ float fast_exp2(float x) {
#if __has_builtin(__builtin_amdgcn_exp2f)
    return __builtin_amdgcn_exp2f(x);
#else
    return exp2f(x);
#endif
}

// pack two floats to a bf16x2 dword.  gfx950 has v_cvt_pk_bf16_f32 (1 op,
// RNE); fallback = round-half-up bit trick (3 ops).
__device__ __forceinline__ unsigned int pack_bf16_2(float lo, float hi) {
#if __has_builtin(__builtin_amdgcn_cvt_pk_bf16_f32)
    auto pk = __builtin_amdgcn_cvt_pk_bf16_f32(lo, hi);
    return *(const unsigned int*)&pk;
#else
    unsigned int ulo = __builtin_bit_cast(unsigned int, lo) + 0x8000u;
    unsigned int uhi = __builtin_bit_cast(unsigned int, hi) + 0x8000u;
#if __has_builtin(__builtin_amdgcn_perm)
    return __builtin_amdgcn_perm(uhi, ulo, 0x07060302u);
#else
    return (uhi & 0xFFFF0000u) | (ulo >> 16);
#endif
#endif
}

// async global->LDS, 16B per lane
__device__ __forceinline__ void gl16(const void* g, void* l) {
    __builtin_amdgcn_global_load_lds(
        (__attribute__((address_space(1))) const void*)g,
        (__attribute__((address_space(3))) void*)l, 16, 0, 0);
}

// ---------------------------------------------------------------------------
// Kernel 0: fp32->bf16: x->xb; w_qkv row-permuted (slot s = c*1024+h*64+d) ->
// wqp; w_proj->wpb.  Block 4096: permuted (+Q-prescaled) bias -> bias_perm.
// ---------------------------------------------------------------------------
__global__ __launch_bounds__(256) void convert_kernel(
    const float* __restrict__ x, const float* __restrict__ wq,
    const float* __restrict__ wp, const float* __restrict__ b_qkv,
    unsigned short* __restrict__ xb, unsigned short* __restrict__ wqp,
    unsigned short* __restrict__ wpb, float* __restrict__ bias_perm)
{
    if (blockIdx.x == 4096) {
        for (int q = threadIdx.x; q < E3_; q += 256) {
            const int c = q >> 10, rem = q & 1023;
            const int h = rem >> 6, d = rem & 63;
            float v = b_qkv[h * 192 + d * 3 + c];
            if (c == 0) v *= QSCALE;
            bias_perm[q] = v;
        }
        return;
    }
    const int o = (blockIdx.x * 256 + threadIdx.x) * 8;
    const float* src;
    unsigned short* dst;
    if (o < 4194304) {                     // x: 4M
        src = x + o; dst = xb + o;
    } else if (o < 7340032) {              // w_qkv permuted: 3M
        const int oo = o - 4194304;
        const int s = oo >> 10, k = oo & 1023;
        const int c = s >> 10, rem = s & 1023;
        const int h = rem >> 6, d = rem & 63;
        src = wq + (size_t)(h * 192 + d * 3 + c) * E_ + k;
        dst = wqp + oo;
    } else {                               // w_proj: 1M
        const int oo = o - 7340032;
        src = wp + oo; dst = wpb + oo;
    }
    float4 a = *(const float4*)src;
    float4 b = *(const float4*)(src + 4);
    uint2v p0, p1;
    p0.x = pack_bf16_2(a.x, a.y); p0.y = pack_bf16_2(a.z, a.w);
    p1.x = pack_bf16_2(b.x, b.y); p1.y = pack_bf16_2(b.z, b.w);
    *(uint2v*)dst = p0;
    *(uint2v*)(dst + 4) = p1;
}

#define GEMM_PROLOG                                                          \
    const int t    = threadIdx.x;                                            \
    const int wv   = t >> 6, lane = t & 63;                                  \
    const int quad = lane >> 4, l15 = lane & 15;                             \
    const int wr   = wv & 1, wc = wv >> 1;                                   \
    f32x4 acc[4][4];                                                         \
    _Pragma("unroll")                                                        \
    for (int i = 0; i < 4; ++i)                                              \
        _Pragma("unroll")                                                    \
        for (int j = 0; j < 4; ++j) acc[i][j] = (f32x4){0.f, 0.f, 0.f, 0.f};

// ---------------------------------------------------------------------------
// Kernel 1: merged qkv GEMM over all 3072 output slots (grid 24 x 32).
// 128x128 tile, BK=32, 4 waves (2x2), global_load_lds(16B), XOR-swizzled
// LDS, 2-buffer ping-pong + __syncthreads (R6-verified).  BK stays 32:
// BK=64 would need 64KB LDS -> 2 blocks/CU vs the grid's 3/CU (m132 trap).
// r13: XCD-aware block swizzle (T1), 768 = 8*96 bijective.
// r14: V-branch stores VT key-paired (slot gi*8+hi*4+j) -> attn PV at K=32.
// r17: staging addresses hoisted to per-lane base pointers; fragment LDS
// offsets precomputed.
// ---------------------------------------------------------------------------
__global__ __launch_bounds__(256) void qkv_kernel(
    const unsigned short* __restrict__ A, const unsigned short* __restrict__ Bm,
    const float* __restrict__ bias_perm,
    unsigned short* __restrict__ Q, unsigned short* __restrict__ K,
    unsigned short* __restrict__ VT)
{
    __shared__ __attribute__((aligned(16))) unsigned short As[2][128 * 32];
    __shared__ __attribute__((aligned(16))) unsigned short Bs[2][128 * 32];
    GEMM_PROLOG
    // XCD swizzle: HW round-robins original linear id across 8 XCDs.
    const int lid = blockIdx.x + 24 * blockIdx.y;        // 0..767
    const int swz = (lid & 7) * 96 + (lid >> 3);         // bijective (768=8*96)
    const int bx  = swz % 24, by = swz / 24;
    const int bm = by * 128;   // token rows
    const int bn = bx * 128;   // s slots
    const int c  = bn >> 10;   // 0=Q,1=K,2=V (uniform per block)

    // --- r17 hoisted staging bases (identical address algebra to r13) ---
    const int chunk0 = wv * 128 + lane;
    const int row0   = chunk0 >> 2;
    const int g0     = ((chunk0 & 3) ^ ((row0 >> 1) & 3)) * 8;
    const int chunk1 = chunk0 + 64;
    const int row1   = chunk1 >> 2;
    const int g1     = ((chunk1 & 3) ^ ((row1 >> 1) & 3)) * 8;
    const unsigned short* aS0 = A  + (size_t)(bm + row0) * E_ + g0;
    const unsigned short* aS1 = A  + (size_t)(bm + row1) * E_ + g1;
    const unsigned short* bS0 = Bm + (size_t)(bn + row0) * E_ + g0;
    const unsigned short* bS1 = Bm + (size_t)(bn + row1) * E_ + g1;
    const int ldsOff0 = wv * 1024;        // shorts: (wv*128+ 0)*8
    const int ldsOff1 = wv * 1024 + 512;  // shorts: (wv*128+64)*8

#define QKV_STAGE(buf, k0)                                                   \
    {                                                                        \
        gl16(aS0 + (k0), &As[buf][ldsOff0]);                                 \
        gl16(bS0 + (k0), &Bs[buf][ldsOff0]);                                 \
        gl16(aS1 + (k0), &As[buf][ldsOff1]);                                 \
        gl16(bS1 + (k0), &Bs[buf][ldsOff1]);                                 \
    }

    // --- r17 hoisted fragment offsets (loop-invariant) ---
    const int sw = (l15 >> 1) & 3;
    int offM[4], offN[4];
#pragma unroll
    for (int i = 0; i < 4; ++i) {
        offM[i] = (wr * 64 + i * 16 + l15) * 32 + ((quad ^ sw) * 8);
        offN[i] = (wc * 64 + i * 16 + l15) * 32 + ((quad ^ sw) * 8);
    }

    QKV_STAGE(0, 0);
    if (c < 2) {
        for (int it = 0; it < 32; ++it) {
            const int cur = it & 1;
            __syncthreads();
            if (it < 31) QKV_STAGE(cur ^ 1, (it + 1) * 32);
            short8 af[4], bf[4];
#pragma unroll
            for (int i = 0; i < 4; ++i) {
                af[i] = *(const short8*)&Bs[cur][offM[i]];   // m = s slots
                bf[i] = *(const short8*)&As[cur][offN[i]];   // n = tokens
            }
#pragma unroll
            for (int i = 0; i < 4; ++i)
#pragma unroll
                for (int j = 0; j < 4; ++j)
                    acc[i][j] = MFMA16(af[i], bf[j], acc[i][j]);  // D[m=s][n=tok]
        }
        const float scale = (c == 0) ? QSCALE : 1.0f;
        unsigned short* dst0 = (c == 0) ? Q : K;
#pragma unroll
        for (int i = 0; i < 4; ++i) {
            const int s0 = bn + wr * 64 + i * 16 + quad * 4;
            const int h  = (s0 >> 6) & 15;
            const int d0 = s0 & 63;
            const float4 bq = *(const float4*)(bias_perm + s0);
#pragma unroll
            for (int j = 0; j < 4; ++j) {
                const int row = bm + wc * 64 + j * 16 + l15;
                const int b   = row >> 11, n = row & (N_ - 1);
                const float v0 = fmaf(acc[i][j][0], scale, bq.x);
                const float v1 = fmaf(acc[i][j][1], scale, bq.y);
                const float v2 = fmaf(acc[i][j][2], scale, bq.z);
                const float v3 = fmaf(acc[i][j][3], scale, bq.w);
                uint2v pk;
                pk.x = pack_bf16_2(v0, v1);
                pk.y = pack_bf16_2(v2, v3);
                *(uint2v*)(dst0 + (((size_t)b * H_ + h) * N_ + n) * D_ + d0) = pk;
            }
        }
    } else {
        for (int it = 0; it < 32; ++it) {
            const int cur = it & 1;
            __syncthreads();
            if (it < 31) QKV_STAGE(cur ^ 1, (it + 1) * 32);
            short8 af[4], bf[4];
#pragma unroll
            for (int i = 0; i < 4; ++i) {
                af[i] = *(const short8*)&As[cur][offM[i]];   // m = tokens
                bf[i] = *(const short8*)&Bs[cur][offN[i]];   // n = s slots
            }
#pragma unroll
            for (int i = 0; i < 4; ++i)
#pragma unroll
                for (int j = 0; j < 4; ++j)
                    acc[i][j] = MFMA16(af[i], bf[j], acc[i][j]);  // D[m=tok][n=s]
        }
#pragma unroll
        for (int j = 0; j < 4; ++j) {
            const int s = bn + wc * 64 + j * 16 + l15;
            const int h = (s >> 6) & 15, d = s & 63;
            const float bv = bias_perm[s];
#pragma unroll
            for (int i = 0; i < 4; ++i) {
                const int row0v = bm + wr * 64 + i * 16 + quad * 4;
                const int b     = row0v >> 11, n0 = row0v & (N_ - 1);
                // r14 key-pair permutation (bijective on 4-aligned groups):
                // np = (n0 & ~31) | gi*8 + hi*4, gi = (n0>>2)&3, hi = (n0>>4)&1
                const int np = (n0 & ~31) | ((((n0 >> 2) & 3) << 3) + (((n0 >> 4) & 1) << 2));
                uint2v pk;
                pk.x = pack_bf16_2(acc[i][j][0] + bv, acc[i][j][1] + bv);
                pk.y = pack_bf16_2(acc[i][j][2] + bv, acc[i][j][3] + bv);
                *(uint2v*)(VT + (((size_t)b * H_ + h) * D_ + d) * N_ + np) = pk;
            }
        }
    }
#undef QKV_STAGE
}

// ---------------------------------------------------------------------------
// Kernel 2: flash attention, 2x2 hybrid partition (r10 sync structure).
// Wave (wq,wk): q-rows [wq*32,+32), keys [wk*32,+32).  S^T = K_own.Q_own;
// P stays in registers as the A-operand.
// r15: PV and l = P.1 at K=32 (16x16x32 A/B k-map is k = quad*8+e; the r14
// VT slot order kappa equals concat(pa[kb0], pa[kb1])).
// r17: staging bases + inner LDS offsets hoisted out of the kt loop.
// r18: __launch_bounds__(256,4) — verified clean on replay (r11/r12
// failures were confounds); per-dispatch 52.4 -> 50.4 us.
// PV: 8 MFMAs/kt, lsum: 2, QK: 8 -> 18 passes/kt.
// LDS: 32 KB tile pool (dbuf K+V) + 512 B lsum.
// ---------------------------------------------------------------------------
__global__ __launch_bounds__(256, 4) void attn_kernel(
    const unsigned short* __restrict__ Q, const unsigned short* __restrict__ K,
    const unsigned short* __restrict__ VT, unsigned short* __restrict__ CTX)
{
    __shared__ __attribute__((aligned(16))) unsigned short pool[16384]; // Ks[2]|Vs[2]
    __shared__ float lsumBuf[2][64];   // [wk][q]

    const int t    = threadIdx.x;
    const int wv   = t >> 6, lane = t & 63;
    const int quad = lane >> 4, l15 = lane & 15;
    const int wq   = wv & 1, wk = wv >> 1;
    const int qt   = blockIdx.x & 31;   // N/64 q-tiles
    const int bh   = blockIdx.x >> 5;

    const unsigned short* Kp = K + (size_t)bh * N_ * D_;
    const unsigned short* Vp = VT + (size_t)bh * D_ * N_;

    // Q B-frags for this wave's 2 q-subtiles (global subtiles wq*2+s)
    short8 qf[2][2];
#pragma unroll
    for (int s = 0; s < 2; ++s) {
        const unsigned short* Qp =
            Q + ((size_t)bh * N_ + qt * 64 + (wq * 2 + s) * 16 + l15) * D_;
        qf[s][0] = *(const short8*)(Qp + quad * 8);
        qf[s][1] = *(const short8*)(Qp + 32 + quad * 8);
    }

    // --- r17 hoisted staging bases (identical algebra to r10 macro) ---
    const int cch0 = (wv * 2) * 64 + lane;
    const int srow0 = cch0 >> 3;
    const int sgc0  = ((cch0 & 7) ^ (srow0 & 7)) * 8;
    const int cch1 = cch0 + 64;
    const int srow1 = cch1 >> 3;
    const int sgc1  = ((cch1 & 7) ^ (srow1 & 7)) * 8;
    const unsigned short* kS0 = Kp + (size_t)srow0 * D_ + sgc0;
    const unsigned short* kS1 = Kp + (size_t)srow1 * D_ + sgc1;
    const unsigned short* vS0 = Vp + (size_t)srow0 * N_ + sgc0;
    const unsigned short* vS1 = Vp + (size_t)srow1 * N_ + sgc1;
    const int aOff0 = (wv * 2) * 512, aOff1 = aOff0 + 512;

#define ATTN_STAGE(buf, kt)                                                  \
    {                                                                        \
        gl16(kS0 + (kt) * (64 * D_), &pool[(buf) * 4096 + aOff0]);           \
        gl16(vS0 + (kt) * 64,        &pool[8192 + (buf) * 4096 + aOff0]);    \
        gl16(kS1 + (kt) * (64 * D_), &pool[(buf) * 4096 + aOff1]);           \
        gl16(vS1 + (kt) * 64,        &pool[8192 + (buf) * 4096 + aOff1]);    \
    }

    // --- r17 hoisted inner LDS read offsets (loop-invariant) ---
    const int koff0 = (quad ^ (l15 & 7)) * 8;
    const int koff1 = ((4 + quad) ^ (l15 & 7)) * 8;
    const int vs128 = ((wk * 4 + quad) ^ (l15 & 7)) * 8;
    int kOff0[2], kOff1[2], vOff[4];
#pragma unroll
    for (int kb = 0; kb < 2; ++kb) {
        const int krow = (wk * 32 + kb * 16 + l15) * 64;
        kOff0[kb] = krow + koff0;
        kOff1[kb] = krow + koff1;
    }
#pragma unroll
    for (int nt = 0; nt < 4; ++nt)
        vOff[nt] = (nt * 16 + l15) * 64 + vs128;

    // bf16 1.0 x8 for the l = P.1 MFMA (K=32)
    short8 ones8;
#pragma unroll
    for (int i = 0; i < 8; ++i) ones8[i] = (short)0x3F80;

    f32x4 O[2][4];   // [q-subtile][nt] partial over this wave's 32 keys
#pragma unroll
    for (int s = 0; s < 2; ++s)
#pragma unroll
        for (int nt = 0; nt < 4; ++nt) O[s][nt] = (f32x4){0.f, 0.f, 0.f, 0.f};
    f32x4 Lacc[2] = {{0.f, 0.f, 0.f, 0.f}, {0.f, 0.f, 0.f, 0.f}};

    ATTN_STAGE(0, 0);

    for (int kt = 0; kt < 32; ++kt) {
        const int cur = kt & 1;
        __syncthreads();
        if (kt < 31) ATTN_STAGE(cur ^ 1, kt + 1);

        const unsigned short* Kc = pool + cur * 4096;
        const unsigned short* Vc = pool + 8192 + cur * 4096;

        // S^T per key-group kb (16 keys) x q-subtile s
        f32x4 st[2][2];
#pragma unroll
        for (int kb = 0; kb < 2; ++kb) {
            const short8 kf0 = *(const short8*)&Kc[kOff0[kb]];
            const short8 kf1 = *(const short8*)&Kc[kOff1[kb]];
#pragma unroll
            for (int s = 0; s < 2; ++s) {
                st[kb][s] = (f32x4){0.f, 0.f, 0.f, 0.f};
                st[kb][s] = MFMA16(kf0, qf[s][0], st[kb][s]);
                st[kb][s] = MFMA16(kf1, qf[s][1], st[kb][s]);
            }
        }

        // softmax numerator: p = exp2(s), packed straight into the K=32
        // A-operand slot order: e<4 = kb0 keys quad*4+e, e>=4 = kb1 keys
        // 16+quad*4+(e-4)  (= r14 VT slot order kappa).
        short8 pa8[2];
#pragma unroll
        for (int s = 0; s < 2; ++s) {
            uint4v u;
            u.x = pack_bf16_2(fast_exp2(st[0][s][0]), fast_exp2(st[0][s][1]));
            u.y = pack_bf16_2(fast_exp2(st[0][s][2]), fast_exp2(st[0][s][3]));
            u.z = pack_bf16_2(fast_exp2(st[1][s][0]), fast_exp2(st[1][s][1]));
            u.w = pack_bf16_2(fast_exp2(st[1][s][2]), fast_exp2(st[1][s][3]));
            pa8[s] = __builtin_bit_cast(short8, u);
        }

        // l partials via MFMA (K=32): Lacc[s] += P[s] . 1
#pragma unroll
        for (int s = 0; s < 2; ++s)
            Lacc[s] = MFMA16(pa8[s], ones8, Lacc[s]);

        // PV (K=32): O[s][nt] += P[s] . V(all 32 keys of this wave);
        // one b128 read + one MFMA per (s,nt)
#pragma unroll
        for (int nt = 0; nt < 4; ++nt) {
            const short8 v8 = *(const short8*)&Vc[vOff[nt]];
#pragma unroll
            for (int s = 0; s < 2; ++s)
                O[s][nt] = MFMA16(pa8[s], v8, O[s][nt]);
        }
    }
#undef ATTN_STAGE

    // Lacc D-layout: row q_local = quad*4+g, all 16 cols identical -> lane
    // l15==0 of each quad publishes its 4 q rows.
    if (l15 == 0) {
#pragma unroll
        for (int s = 0; s < 2; ++s)
#pragma unroll
            for (int g = 0; g < 4; ++g)
                lsumBuf[wk][wq * 32 + s * 16 + quad * 4 + g] = Lacc[s][g];
    }
    __syncthreads();   // tile reads done (pool reusable) + lsumBuf visible

    // O D-layout: q = quad*4+g (row), d = nt*16 + l15 (col)
    float* red = (float*)pool;   // 8192 floats; [wq][qsub 0..31][d 0..63]
    if (wk == 1) {
#pragma unroll
        for (int s = 0; s < 2; ++s)
#pragma unroll
            for (int nt = 0; nt < 4; ++nt)
#pragma unroll
                for (int g = 0; g < 4; ++g)
                    red[wq * 2048 + (s * 16 + quad * 4 + g) * 64 + nt * 16 + l15] =
                        O[s][nt][g];
    }
    __syncthreads();

    if (wk == 0) {
        const int b = bh >> 4, h = bh & 15;
#pragma unroll
        for (int s = 0; s < 2; ++s) {
            float inv[4];
#pragma unroll
            for (int g = 0; g < 4; ++g) {
                const int q = wq * 32 + s * 16 + quad * 4 + g;
                inv[g] = 1.0f / (lsumBuf[0][q] + lsumBuf[1][q]);
            }
#pragma unroll
            for (int nt = 0; nt < 4; ++nt) {
#pragma unroll
                for (int g = 0; g < 4; ++g) {
                    const float o = O[s][nt][g] +
                        red[wq * 2048 + (s * 16 + quad * 4 + g) * 64 + nt * 16 + l15];
                    const int qrow = qt * 64 + wq * 32 + s * 16 + quad * 4 + g;
                    CTX[((size_t)b * N_ + qrow) * E_ + h * D_ + nt * 16 + l15] =
                        f2bf(o * inv[g]);
                }
            }
        }
    }
}

// ---------------------------------------------------------------------------
// Kernel 3: out = ctx @ w_proj^T + b_proj.  128(M) x 64(N) tiles -> 512
// blocks = 2/CU.  C^T orientation -> float4 stores.
// r13: XCD-aware block swizzle (T1), 512 = 8*64 bijective.
// r17: staging bases + fragment offsets hoisted.
// r19: BK=64 via paired 32-wide half-buffers — 16 iterations instead of 32
// (half the barrier drains), 16 MFMA/wave/iter.  Each half-buffer is an
// exact clone of the old 32-wide buffer (same swizzle, same fragment
// offsets); K order 64it -> 64it+32 preserved -> bit-exact.  LDS 48 KB
// allows 3 blocks/CU; grid only asks 2 -> zero occupancy cost (m132 trap
// avoided; qkv deliberately NOT given BK=64 for that reason).
// ---------------------------------------------------------------------------
__global__ __launch_bounds__(256) void proj_kernel(
    const unsigned short* __restrict__ A, const unsigned short* __restrict__ Bm,
    const float* __restrict__ bias, float* __restrict__ out)
{
    __shared__ __attribute__((aligned(16))) unsigned short As[2][2][128 * 32];
    __shared__ __attribute__((aligned(16))) unsigned short Bs[2][2][64 * 32];
    const int t    = threadIdx.x;
    const int wv   = t >> 6, lane = t & 63;
    const int quad = lane >> 4, l15 = lane & 15;
    const int wr   = wv & 1, wc = wv >> 1;
    const int lid  = blockIdx.x + 16 * blockIdx.y;       // 0..511
    const int swz  = (lid & 7) * 64 + (lid >> 3);        // bijective (512=8*64)
    const int bx   = swz & 15, by = swz >> 4;
    const int bm   = by * 128;   // ctx rows
    const int bn   = bx * 64;    // out cols

    f32x4 acc[2][4];
#pragma unroll
    for (int i = 0; i < 2; ++i)
#pragma unroll
        for (int j = 0; j < 4; ++j) acc[i][j] = (f32x4){0.f, 0.f, 0.f, 0.f};

    // --- r17 hoisted staging bases ---
    const int pc0 = wv * 128 + lane, pr0 = pc0 >> 2;
    const int pg0 = ((pc0 & 3) ^ ((pr0 >> 1) & 3)) * 8;
    const int pc1 = pc0 + 64, pr1 = pc1 >> 2;
    const int pg1 = ((pc1 & 3) ^ ((pr1 >> 1) & 3)) * 8;
    const int pcB = wv * 64 + lane, prB = pcB >> 2;
    const int pgB = ((pcB & 3) ^ ((prB >> 1) & 3)) * 8;
    const unsigned short* aS0 = A  + (size_t)(bm + pr0) * E_ + pg0;
    const unsigned short* aS1 = A  + (size_t)(bm + pr1) * E_ + pg1;
    const unsigned short* bS  = Bm + (size_t)(bn + prB) * E_ + pgB;
    const int ldsA0 = wv * 1024, ldsA1 = wv * 1024 + 512, ldsB0 = wv * 512;

// r19: stage BOTH 32-wide halves of K-pair it2 (K cols [it2*64, it2*64+64))
#define PROJ_STAGE(buf, it2)                                                 \
    {                                                                        \
        gl16(aS0 + (it2) * 64,      &As[buf][0][ldsA0]);                     \
        gl16(aS1 + (it2) * 64,      &As[buf][0][ldsA1]);                     \
        gl16(bS  + (it2) * 64,      &Bs[buf][0][ldsB0]);                     \
        gl16(aS0 + (it2) * 64 + 32, &As[buf][1][ldsA0]);                     \
        gl16(aS1 + (it2) * 64 + 32, &As[buf][1][ldsA1]);                     \
        gl16(bS  + (it2) * 64 + 32, &Bs[buf][1][ldsB0]);                     \
    }

    // --- r17 hoisted fragment offsets ---
    const int sw = (l15 >> 1) & 3;
    int offPM[2], offPN[4];
#pragma unroll
    for (int i = 0; i < 2; ++i)
        offPM[i] = (wr * 32 + i * 16 + l15) * 32 + ((quad ^ sw) * 8);
#pragma unroll
    for (int j = 0; j < 4; ++j)
        offPN[j] = (wc * 64 + j * 16 + l15) * 32 + ((quad ^ sw) * 8);

    PROJ_STAGE(0, 0);
    for (int it = 0; it < 16; ++it) {
        const int cur = it & 1;
        __syncthreads();
        if (it < 15) PROJ_STAGE(cur ^ 1, it + 1);
#pragma unroll
        for (int h = 0; h < 2; ++h) {
            short8 af[2], bf[4];
#pragma unroll
            for (int i = 0; i < 2; ++i)
                af[i] = *(const short8*)&Bs[cur][h][offPM[i]];
#pragma unroll
            for (int j = 0; j < 4; ++j)
                bf[j] = *(const short8*)&As[cur][h][offPN[j]];
#pragma unroll
            for (int i = 0; i < 2; ++i)
#pragma unroll
                for (int j = 0; j < 4; ++j)
                    acc[i][j] = MFMA16(af[i], bf[j], acc[i][j]);  // D[m=col][n=row]
        }
    }
#undef PROJ_STAGE

#pragma unroll
    for (int i = 0; i < 2; ++i) {
        const int col0 = bn + wr * 32 + i * 16 + quad * 4;
        const float4 bp = *(const float4*)(bias + col0);
#pragma unroll
        for (int j = 0; j < 4; ++j) {
            const int row = bm + wc * 64 + j * 16 + l15;
            float4 o;
            o.x = acc[i][j][0] + bp.x;
            o.y = acc[i][j][1] + bp.y;
            o.z = acc[i][j][2] + bp.z;
            o.w = acc[i][j][3] + bp.w;
            *(float4*)(out + (size_t)row * E_ + col0) = o;
        }
    }
}

// ---------------------------------------------------------------------------
extern "C" void kernel_launch(void* const* d_in, const int* in_sizes, int n_in,
                              void* d_out, int out_size, void* d_ws, size_t ws_size,
                              hipStream_t stream)
{
    const float* x      = (const float*)d_in[0];
    const float* w_qkv  = (const float*)d_in[1];
    const float* b_qkv  = (const float*)d_in[2];
    const float* w_proj = (const float*)d_in[3];
    const float* b_proj = (const float*)d_in[4];
    float* out = (float*)d_out;

    // ws (bf16 elems): xb 4M | wqp 3M | wpb 1M | Q 4M | K 4M | VT 4M | CTX 4M
    // then bias_perm (3072 fp32)
    unsigned short* xb  = (unsigned short*)d_ws;
    unsigned short* wqp = xb  + 4194304;
    unsigned short* wpb = wqp + 3145728;
    unsigned short* Q   = wpb + 1048576;
    unsigned short* K   = Q   + 4194304;
    unsigned short* VT  = K   + 4194304;
    unsigned short* CTX = VT  + 4194304;
    float* bias_perm    = (float*)(CTX + 4194304);

    dim3 blk(256);
    convert_kernel<<<dim3(4097), blk, 0, stream>>>(
        x, w_qkv, w_proj, b_qkv, xb, wqp, wpb, bias_perm);

    qkv_kernel<<<dim3(24, 32), blk, 0, stream>>>(xb, wqp, bias_perm, Q, K, VT);

    attn_kernel<<<dim3(B_ * H_ * (N_ / 64)), blk, 0, stream>>>(Q, K, VT, CTX);

    proj_kernel<<<dim3(16, 32), blk, 0, stream>>>(CTX, wpb, b_proj, out);
}

// Round 11
// 189.623 us; speedup vs baseline: 1.0242x; 1.0103x over previous
//
#include <hip/hip_runtime.h>
#include <hip/hip_bf16.h>
#include <math.h>

#define B_   2
#define N_   2048
#define E_   1024
#define H_   16
#define D_   64
#define E3_  3072
#define M_   (B_ * N_)   // 4096

// log2(e)/8 folded into Q so softmax inner loop is a bare exp2
#define QSCALE 0.18033688011112042f

using short8  = __attribute__((ext_vector_type(8))) short;
using short4v = __attribute__((ext_vector_type(4))) short;
using f32x4   = __attribute__((ext_vector_type(4))) float;
using uint2v  = __attribute__((ext_vector_type(2))) unsigned int;
using uint4v  = __attribute__((ext_vector_type(4))) unsigned int;

#define MFMA16(a, b, c)    __builtin_amdgcn_mfma_f32_16x16x32_bf16((a), (b), (c), 0, 0, 0)

__device__ __forceinline__ unsigned short f2bf(float f) {
    __hip_bfloat16 h = __float2bfloat16(f);
    return __builtin_bit_cast(unsigned short, h);
}

__device__ __forceinline__ float fast_exp2(float x) {
#if __has_builtin(__builtin_amdgcn_exp2f)
    return __builtin_amdgcn_exp2f(x);
#else
    return exp2f(x);
#endif
}

// pack two floats to a bf16x2 dword.  gfx950 has v_cvt_pk_bf16_f32 (1 op,
// RNE); fallback = round-half-up bit trick (3 ops).
__device__ __forceinline__ unsigned int pack_bf16_2(float lo, float hi) {
#if __has_builtin(__builtin_amdgcn_cvt_pk_bf16_f32)
    auto pk = __builtin_amdgcn_cvt_pk_bf16_f32(lo, hi);
    return *(const unsigned int*)&pk;
#else
    unsigned int ulo = __builtin_bit_cast(unsigned int, lo) + 0x8000u;
    unsigned int uhi = __builtin_bit_cast(unsigned int, hi) + 0x8000u;
#if __has_builtin(__builtin_amdgcn_perm)
    return __builtin_amdgcn_perm(uhi, ulo, 0x07060302u);
#else
    return (uhi & 0xFFFF0000u) | (ulo >> 16);
#endif
#endif
}

// async global->LDS, 16B per lane
__device__ __forceinline__ void gl16(const void* g, void* l) {
    __builtin_amdgcn_global_load_lds(
        (__attribute__((address_space(1))) const void*)g,
        (__attribute__((address_space(3))) void*)l, 16, 0, 0);
}

// ---------------------------------------------------------------------------
// Kernel 0: fp32->bf16: x->xb; w_qkv row-permuted (slot s = c*1024+h*64+d) ->
// wqp; w_proj->wpb.  Block 4096: permuted (+Q-prescaled) bias -> bias_perm.
// ---------------------------------------------------------------------------
__global__ __launch_bounds__(256) void convert_kernel(
    const float* __restrict__ x, const float* __restrict__ wq,
    const float* __restrict__ wp, const float* __restrict__ b_qkv,
    unsigned short* __restrict__ xb, unsigned short* __restrict__ wqp,
    unsigned short* __restrict__ wpb, float* __restrict__ bias_perm)
{
    if (blockIdx.x == 4096) {
        for (int q = threadIdx.x; q < E3_; q += 256) {
            const int c = q >> 10, rem = q & 1023;
            const int h = rem >> 6, d = rem & 63;
            float v = b_qkv[h * 192 + d * 3 + c];
            if (c == 0) v *= QSCALE;
            bias_perm[q] = v;
        }
        return;
    }
    const int o = (blockIdx.x * 256 + threadIdx.x) * 8;
    const float* src;
    unsigned short* dst;
    if (o < 4194304) {                     // x: 4M
        src = x + o; dst = xb + o;
    } else if (o < 7340032) {              // w_qkv permuted: 3M
        const int oo = o - 4194304;
        const int s = oo >> 10, k = oo & 1023;
        const int c = s >> 10, rem = s & 1023;
        const int h = rem >> 6, d = rem & 63;
        src = wq + (size_t)(h * 192 + d * 3 + c) * E_ + k;
        dst = wqp + oo;
    } else {                               // w_proj: 1M
        const int oo = o - 7340032;
        src = wp + oo; dst = wpb + oo;
    }
    float4 a = *(const float4*)src;
    float4 b = *(const float4*)(src + 4);
    uint2v p0, p1;
    p0.x = pack_bf16_2(a.x, a.y); p0.y = pack_bf16_2(a.z, a.w);
    p1.x = pack_bf16_2(b.x, b.y); p1.y = pack_bf16_2(b.z, b.w);
    *(uint2v*)dst = p0;
    *(uint2v*)(dst + 4) = p1;
}

#define GEMM_PROLOG                                                          \
    const int t    = threadIdx.x;                                            \
    const int wv   = t >> 6, lane = t & 63;                                  \
    const int quad = lane >> 4, l15 = lane & 15;                             \
    const int wr   = wv & 1, wc = wv >> 1;                                   \
    f32x4 acc[4][4];                                                         \
    _Pragma("unroll")                                                        \
    for (int i = 0; i < 4; ++i)                                              \
        _Pragma("unroll")                                                    \
        for (int j = 0; j < 4; ++j) acc[i][j] = (f32x4){0.f, 0.f, 0.f, 0.f};

// ---------------------------------------------------------------------------
// Kernel 1: merged qkv GEMM over all 3072 output slots (grid 24 x 32).
// 128x128 tile, BK=32, 4 waves (2x2), global_load_lds(16B), XOR-swizzled
// LDS, 2-buffer ping-pong + __syncthreads (R6-verified).  BK stays 32:
// BK=64 would need 64KB LDS -> 2 blocks/CU vs the grid's 3/CU (m132 trap).
// r13: XCD-aware block swizzle (T1), 768 = 8*96 bijective.
// r14: V-branch stores VT key-paired (slot gi*8+hi*4+j) -> attn PV at K=32.
// r17: staging addresses hoisted to per-lane base pointers; fragment LDS
// offsets precomputed.
// ---------------------------------------------------------------------------
__global__ __launch_bounds__(256) void qkv_kernel(
    const unsigned short* __restrict__ A, const unsigned short* __restrict__ Bm,
    const float* __restrict__ bias_perm,
    unsigned short* __restrict__ Q, unsigned short* __restrict__ K,
    unsigned short* __restrict__ VT)
{
    __shared__ __attribute__((aligned(16))) unsigned short As[2][128 * 32];
    __shared__ __attribute__((aligned(16))) unsigned short Bs[2][128 * 32];
    GEMM_PROLOG
    // XCD swizzle: HW round-robins original linear id across 8 XCDs.
    const int lid = blockIdx.x + 24 * blockIdx.y;        // 0..767
    const int swz = (lid & 7) * 96 + (lid >> 3);         // bijective (768=8*96)
    const int bx  = swz % 24, by = swz / 24;
    const int bm = by * 128;   // token rows
    const int bn = bx * 128;   // s slots
    const int c  = bn >> 10;   // 0=Q,1=K,2=V (uniform per block)

    // --- r17 hoisted staging bases (identical address algebra to r13) ---
    const int chunk0 = wv * 128 + lane;
    const int row0   = chunk0 >> 2;
    const int g0     = ((chunk0 & 3) ^ ((row0 >> 1) & 3)) * 8;
    const int chunk1 = chunk0 + 64;
    const int row1   = chunk1 >> 2;
    const int g1     = ((chunk1 & 3) ^ ((row1 >> 1) & 3)) * 8;
    const unsigned short* aS0 = A  + (size_t)(bm + row0) * E_ + g0;
    const unsigned short* aS1 = A  + (size_t)(bm + row1) * E_ + g1;
    const unsigned short* bS0 = Bm + (size_t)(bn + row0) * E_ + g0;
    const unsigned short* bS1 = Bm + (size_t)(bn + row1) * E_ + g1;
    const int ldsOff0 = wv * 1024;        // shorts: (wv*128+ 0)*8
    const int ldsOff1 = wv * 1024 + 512;  // shorts: (wv*128+64)*8

#define QKV_STAGE(buf, k0)                                                   \
    {                                                                        \
        gl16(aS0 + (k0), &As[buf][ldsOff0]);                                 \
        gl16(bS0 + (k0), &Bs[buf][ldsOff0]);                                 \
        gl16(aS1 + (k0), &As[buf][ldsOff1]);                                 \
        gl16(bS1 + (k0), &Bs[buf][ldsOff1]);                                 \
    }

    // --- r17 hoisted fragment offsets (loop-invariant) ---
    const int sw = (l15 >> 1) & 3;
    int offM[4], offN[4];
#pragma unroll
    for (int i = 0; i < 4; ++i) {
        offM[i] = (wr * 64 + i * 16 + l15) * 32 + ((quad ^ sw) * 8);
        offN[i] = (wc * 64 + i * 16 + l15) * 32 + ((quad ^ sw) * 8);
    }

    QKV_STAGE(0, 0);
    if (c < 2) {
        for (int it = 0; it < 32; ++it) {
            const int cur = it & 1;
            __syncthreads();
            if (it < 31) QKV_STAGE(cur ^ 1, (it + 1) * 32);
            short8 af[4], bf[4];
#pragma unroll
            for (int i = 0; i < 4; ++i) {
                af[i] = *(const short8*)&Bs[cur][offM[i]];   // m = s slots
                bf[i] = *(const short8*)&As[cur][offN[i]];   // n = tokens
            }
#pragma unroll
            for (int i = 0; i < 4; ++i)
#pragma unroll
                for (int j = 0; j < 4; ++j)
                    acc[i][j] = MFMA16(af[i], bf[j], acc[i][j]);  // D[m=s][n=tok]
        }
        const float scale = (c == 0) ? QSCALE : 1.0f;
        unsigned short* dst0 = (c == 0) ? Q : K;
#pragma unroll
        for (int i = 0; i < 4; ++i) {
            const int s0 = bn + wr * 64 + i * 16 + quad * 4;
            const int h  = (s0 >> 6) & 15;
            const int d0 = s0 & 63;
            const float4 bq = *(const float4*)(bias_perm + s0);
#pragma unroll
            for (int j = 0; j < 4; ++j) {
                const int row = bm + wc * 64 + j * 16 + l15;
                const int b   = row >> 11, n = row & (N_ - 1);
                const float v0 = fmaf(acc[i][j][0], scale, bq.x);
                const float v1 = fmaf(acc[i][j][1], scale, bq.y);
                const float v2 = fmaf(acc[i][j][2], scale, bq.z);
                const float v3 = fmaf(acc[i][j][3], scale, bq.w);
                uint2v pk;
                pk.x = pack_bf16_2(v0, v1);
                pk.y = pack_bf16_2(v2, v3);
                *(uint2v*)(dst0 + (((size_t)b * H_ + h) * N_ + n) * D_ + d0) = pk;
            }
        }
    } else {
        for (int it = 0; it < 32; ++it) {
            const int cur = it & 1;
            __syncthreads();
            if (it < 31) QKV_STAGE(cur ^ 1, (it + 1) * 32);
            short8 af[4], bf[4];
#pragma unroll
            for (int i = 0; i < 4; ++i) {
                af[i] = *(const short8*)&As[cur][offM[i]];   // m = tokens
                bf[i] = *(const short8*)&Bs[cur][offN[i]];   // n = s slots
            }
#pragma unroll
            for (int i = 0; i < 4; ++i)
#pragma unroll
                for (int j = 0; j < 4; ++j)
                    acc[i][j] = MFMA16(af[i], bf[j], acc[i][j]);  // D[m=tok][n=s]
        }
#pragma unroll
        for (int j = 0; j < 4; ++j) {
            const int s = bn + wc * 64 + j * 16 + l15;
            const int h = (s >> 6) & 15, d = s & 63;
            const float bv = bias_perm[s];
#pragma unroll
            for (int i = 0; i < 4; ++i) {
                const int row0v = bm + wr * 64 + i * 16 + quad * 4;
                const int b     = row0v >> 11, n0 = row0v & (N_ - 1);
                // r14 key-pair permutation (bijective on 4-aligned groups):
                // np = (n0 & ~31) | gi*8 + hi*4, gi = (n0>>2)&3, hi = (n0>>4)&1
                const int np = (n0 & ~31) | ((((n0 >> 2) & 3) << 3) + (((n0 >> 4) & 1) << 2));
                uint2v pk;
                pk.x = pack_bf16_2(acc[i][j][0] + bv, acc[i][j][1] + bv);
                pk.y = pack_bf16_2(acc[i][j][2] + bv, acc[i][j][3] + bv);
                *(uint2v*)(VT + (((size_t)b * H_ + h) * D_ + d) * N_ + np) = pk;
            }
        }
    }
#undef QKV_STAGE
}

// ---------------------------------------------------------------------------
// Kernel 2: flash attention, 2x2 hybrid partition (r10 sync structure).
// Wave (wq,wk): q-rows [wq*32,+32), keys [wk*32,+32).  S^T = K_own.Q_own;
// P stays in registers as the A-operand.
// r15: PV and l = P.1 at K=32 (16x16x32 A/B k-map is k = quad*8+e; the r14
// VT slot order kappa equals concat(pa[kb0], pa[kb1])).
// r17: staging bases + inner LDS offsets hoisted.  r18: (256,4) verified.
// r20: T1 XCD swizzle — 1024 = 8*128 bijective.  Old mapping scattered the
// 32 blocks of one bh across all 8 XCDs (per-XCD K/V working set 16MB >>
// 4MB L2 -> 1.66x K/V re-fetch, L3-latency stages).  New: XCD x owns bh
// [4x,4x+4) -> per-XCD set Q 1MB + K/V 2MB fits L2; the 4 co-resident
// blocks/CU stage the SAME K/V lines (L2-hot).  Output-invariant remap.
// r20: T5 s_setprio(1) around the lsum+PV MFMA cluster — 4 independent
// blocks/CU give wave role diversity (m191 regime, not m190's lockstep).
// PV: 8 MFMAs/kt, lsum: 2, QK: 8 -> 18 passes/kt.
// LDS: 32 KB tile pool (dbuf K+V) + 512 B lsum.
// ---------------------------------------------------------------------------
__global__ __launch_bounds__(256, 4) void attn_kernel(
    const unsigned short* __restrict__ Q, const unsigned short* __restrict__ K,
    const unsigned short* __restrict__ VT, unsigned short* __restrict__ CTX)
{
    __shared__ __attribute__((aligned(16))) unsigned short pool[16384]; // Ks[2]|Vs[2]
    __shared__ float lsumBuf[2][64];   // [wk][q]

    const int t    = threadIdx.x;
    const int wv   = t >> 6, lane = t & 63;
    const int quad = lane >> 4, l15 = lane & 15;
    const int wq   = wv & 1, wk = wv >> 1;
    // r20: XCD-aware bijective remap (1024 = 8*128)
    const int lid  = blockIdx.x;
    const int swzb = (lid & 7) * 128 + (lid >> 3);
    const int qt   = swzb & 31;   // N/64 q-tiles
    const int bh   = swzb >> 5;

    const unsigned short* Kp = K + (size_t)bh * N_ * D_;
    const unsigned short* Vp = VT + (size_t)bh * D_ * N_;

    // Q B-frags for this wave's 2 q-subtiles (global subtiles wq*2+s)
    short8 qf[2][2];
#pragma unroll
    for (int s = 0; s < 2; ++s) {
        const unsigned short* Qp =
            Q + ((size_t)bh * N_ + qt * 64 + (wq * 2 + s) * 16 + l15) * D_;
        qf[s][0] = *(const short8*)(Qp + quad * 8);
        qf[s][1] = *(const short8*)(Qp + 32 + quad * 8);
    }

    // --- r17 hoisted staging bases (identical algebra to r10 macro) ---
    const int cch0 = (wv * 2) * 64 + lane;
    const int srow0 = cch0 >> 3;
    const int sgc0  = ((cch0 & 7) ^ (srow0 & 7)) * 8;
    const int cch1 = cch0 + 64;
    const int srow1 = cch1 >> 3;
    const int sgc1  = ((cch1 & 7) ^ (srow1 & 7)) * 8;
    const unsigned short* kS0 = Kp + (size_t)srow0 * D_ + sgc0;
    const unsigned short* kS1 = Kp + (size_t)srow1 * D_ + sgc1;
    const unsigned short* vS0 = Vp + (size_t)srow0 * N_ + sgc0;
    const unsigned short* vS1 = Vp + (size_t)srow1 * N_ + sgc1;
    const int aOff0 = (wv * 2) * 512, aOff1 = aOff0 + 512;

#define ATTN_STAGE(buf, kt)                                                  \
    {                                                                        \
        gl16(kS0 + (kt) * (64 * D_), &pool[(buf) * 4096 + aOff0]);           \
        gl16(vS0 + (kt) * 64,        &pool[8192 + (buf) * 4096 + aOff0]);    \
        gl16(kS1 + (kt) * (64 * D_), &pool[(buf) * 4096 + aOff1]);           \
        gl16(vS1 + (kt) * 64,        &pool[8192 + (buf) * 4096 + aOff1]);    \
    }

    // --- r17 hoisted inner LDS read offsets (loop-invariant) ---
    const int koff0 = (quad ^ (l15 & 7)) * 8;
    const int koff1 = ((4 + quad) ^ (l15 & 7)) * 8;
    const int vs128 = ((wk * 4 + quad) ^ (l15 & 7)) * 8;
    int kOff0[2], kOff1[2], vOff[4];
#pragma unroll
    for (int kb = 0; kb < 2; ++kb) {
        const int krow = (wk * 32 + kb * 16 + l15) * 64;
        kOff0[kb] = krow + koff0;
        kOff1[kb] = krow + koff1;
    }
#pragma unroll
    for (int nt = 0; nt < 4; ++nt)
        vOff[nt] = (nt * 16 + l15) * 64 + vs128;

    // bf16 1.0 x8 for the l = P.1 MFMA (K=32)
    short8 ones8;
#pragma unroll
    for (int i = 0; i < 8; ++i) ones8[i] = (short)0x3F80;

    f32x4 O[2][4];   // [q-subtile][nt] partial over this wave's 32 keys
#pragma unroll
    for (int s = 0; s < 2; ++s)
#pragma unroll
        for (int nt = 0; nt < 4; ++nt) O[s][nt] = (f32x4){0.f, 0.f, 0.f, 0.f};
    f32x4 Lacc[2] = {{0.f, 0.f, 0.f, 0.f}, {0.f, 0.f, 0.f, 0.f}};

    ATTN_STAGE(0, 0);

    for (int kt = 0; kt < 32; ++kt) {
        const int cur = kt & 1;
        __syncthreads();
        if (kt < 31) ATTN_STAGE(cur ^ 1, kt + 1);

        const unsigned short* Kc = pool + cur * 4096;
        const unsigned short* Vc = pool + 8192 + cur * 4096;

        // S^T per key-group kb (16 keys) x q-subtile s
        f32x4 st[2][2];
#pragma unroll
        for (int kb = 0; kb < 2; ++kb) {
            const short8 kf0 = *(const short8*)&Kc[kOff0[kb]];
            const short8 kf1 = *(const short8*)&Kc[kOff1[kb]];
#pragma unroll
            for (int s = 0; s < 2; ++s) {
                st[kb][s] = (f32x4){0.f, 0.f, 0.f, 0.f};
                st[kb][s] = MFMA16(kf0, qf[s][0], st[kb][s]);
                st[kb][s] = MFMA16(kf1, qf[s][1], st[kb][s]);
            }
        }

        // softmax numerator: p = exp2(s), packed straight into the K=32
        // A-operand slot order: e<4 = kb0 keys quad*4+e, e>=4 = kb1 keys
        // 16+quad*4+(e-4)  (= r14 VT slot order kappa).
        short8 pa8[2];
#pragma unroll
        for (int s = 0; s < 2; ++s) {
            uint4v u;
            u.x = pack_bf16_2(fast_exp2(st[0][s][0]), fast_exp2(st[0][s][1]));
            u.y = pack_bf16_2(fast_exp2(st[0][s][2]), fast_exp2(st[0][s][3]));
            u.z = pack_bf16_2(fast_exp2(st[1][s][0]), fast_exp2(st[1][s][1]));
            u.w = pack_bf16_2(fast_exp2(st[1][s][2]), fast_exp2(st[1][s][3]));
            pa8[s] = __builtin_bit_cast(short8, u);
        }

        // r20: prioritize this wave through the pure-MFMA stretch (T5)
        __builtin_amdgcn_s_setprio(1);

        // l partials via MFMA (K=32): Lacc[s] += P[s] . 1
#pragma unroll
        for (int s = 0; s < 2; ++s)
            Lacc[s] = MFMA16(pa8[s], ones8, Lacc[s]);

        // PV (K=32): O[s][nt] += P[s] . V(all 32 keys of this wave);
        // one b128 read + one MFMA per (s,nt)
#pragma unroll
        for (int nt = 0; nt < 4; ++nt) {
            const short8 v8 = *(const short8*)&Vc[vOff[nt]];
#pragma unroll
            for (int s = 0; s < 2; ++s)
                O[s][nt] = MFMA16(pa8[s], v8, O[s][nt]);
        }

        __builtin_amdgcn_s_setprio(0);
    }
#undef ATTN_STAGE

    // Lacc D-layout: row q_local = quad*4+g, all 16 cols identical -> lane
    // l15==0 of each quad publishes its 4 q rows.
    if (l15 == 0) {
#pragma unroll
        for (int s = 0; s < 2; ++s)
#pragma unroll
            for (int g = 0; g < 4; ++g)
                lsumBuf[wk][wq * 32 + s * 16 + quad * 4 + g] = Lacc[s][g];
    }
    __syncthreads();   // tile reads done (pool reusable) + lsumBuf visible

    // O D-layout: q = quad*4+g (row), d = nt*16 + l15 (col)
    float* red = (float*)pool;   // 8192 floats; [wq][qsub 0..31][d 0..63]
    if (wk == 1) {
#pragma unroll
        for (int s = 0; s < 2; ++s)
#pragma unroll
            for (int nt = 0; nt < 4; ++nt)
#pragma unroll
                for (int g = 0; g < 4; ++g)
                    red[wq * 2048 + (s * 16 + quad * 4 + g) * 64 + nt * 16 + l15] =
                        O[s][nt][g];
    }
    __syncthreads();

    if (wk == 0) {
        const int b = bh >> 4, h = bh & 15;
#pragma unroll
        for (int s = 0; s < 2; ++s) {
            float inv[4];
#pragma unroll
            for (int g = 0; g < 4; ++g) {
                const int q = wq * 32 + s * 16 + quad * 4 + g;
                inv[g] = 1.0f / (lsumBuf[0][q] + lsumBuf[1][q]);
            }
#pragma unroll
            for (int nt = 0; nt < 4; ++nt) {
#pragma unroll
                for (int g = 0; g < 4; ++g) {
                    const float o = O[s][nt][g] +
                        red[wq * 2048 + (s * 16 + quad * 4 + g) * 64 + nt * 16 + l15];
                    const int qrow = qt * 64 + wq * 32 + s * 16 + quad * 4 + g;
                    CTX[((size_t)b * N_ + qrow) * E_ + h * D_ + nt * 16 + l15] =
                        f2bf(o * inv[g]);
                }
            }
        }
    }
}

// ---------------------------------------------------------------------------
// Kernel 3: out = ctx @ w_proj^T + b_proj.  128(M) x 64(N) tiles -> 512
// blocks = 2/CU.  C^T orientation -> float4 stores.
// r13: XCD-aware block swizzle (T1), 512 = 8*64 bijective.
// r17: staging bases + fragment offsets hoisted.
// r19: BK=64 via paired 32-wide half-buffers (16 iters, bit-exact).
// ---------------------------------------------------------------------------
__global__ __launch_bounds__(256) void proj_kernel(
    const unsigned short* __restrict__ A, const unsigned short* __restrict__ Bm,
    const float* __restrict__ bias, float* __restrict__ out)
{
    __shared__ __attribute__((aligned(16))) unsigned short As[2][2][128 * 32];
    __shared__ __attribute__((aligned(16))) unsigned short Bs[2][2][64 * 32];
    const int t    = threadIdx.x;
    const int wv   = t >> 6, lane = t & 63;
    const int quad = lane >> 4, l15 = lane & 15;
    const int wr   = wv & 1, wc = wv >> 1;
    const int lid  = blockIdx.x + 16 * blockIdx.y;       // 0..511
    const int swz  = (lid & 7) * 64 + (lid >> 3);        // bijective (512=8*64)
    const int bx   = swz & 15, by = swz >> 4;
    const int bm   = by * 128;   // ctx rows
    const int bn   = bx * 64;    // out cols

    f32x4 acc[2][4];
#pragma unroll
    for (int i = 0; i < 2; ++i)
#pragma unroll
        for (int j = 0; j < 4; ++j) acc[i][j] = (f32x4){0.f, 0.f, 0.f, 0.f};

    // --- r17 hoisted staging bases ---
    const int pc0 = wv * 128 + lane, pr0 = pc0 >> 2;
    const int pg0 = ((pc0 & 3) ^ ((pr0 >> 1) & 3)) * 8;
    const int pc1 = pc0 + 64, pr1 = pc1 >> 2;
    const int pg1 = ((pc1 & 3) ^ ((pr1 >> 1) & 3)) * 8;
    const int pcB = wv * 64 + lane, prB = pcB >> 2;
    const int pgB = ((pcB & 3) ^ ((prB >> 1) & 3)) * 8;
    const unsigned short* aS0 = A  + (size_t)(bm + pr0) * E_ + pg0;
    const unsigned short* aS1 = A  + (size_t)(bm + pr1) * E_ + pg1;
    const unsigned short* bS  = Bm + (size_t)(bn + prB) * E_ + pgB;
    const int ldsA0 = wv * 1024, ldsA1 = wv * 1024 + 512, ldsB0 = wv * 512;

// r19: stage BOTH 32-wide halves of K-pair it2 (K cols [it2*64, it2*64+64))
#define PROJ_STAGE(buf, it2)                                                 \
    {                                                                        \
        gl16(aS0 + (it2) * 64,      &As[buf][0][ldsA0]);                     \
        gl16(aS1 + (it2) * 64,      &As[buf][0][ldsA1]);                     \
        gl16(bS  + (it2) * 64,      &Bs[buf][0][ldsB0]);                     \
        gl16(aS0 + (it2) * 64 + 32, &As[buf][1][ldsA0]);                     \
        gl16(aS1 + (it2) * 64 + 32, &As[buf][1][ldsA1]);                     \
        gl16(bS  + (it2) * 64 + 32, &Bs[buf][1][ldsB0]);                     \
    }

    // --- r17 hoisted fragment offsets ---
    const int sw = (l15 >> 1) & 3;
    int offPM[2], offPN[4];
#pragma unroll
    for (int i = 0; i < 2; ++i)
        offPM[i] = (wr * 32 + i * 16 + l15) * 32 + ((quad ^ sw) * 8);
#pragma unroll
    for (int j = 0; j < 4; ++j)
        offPN[j] = (wc * 64 + j * 16 + l15) * 32 + ((quad ^ sw) * 8);

    PROJ_STAGE(0, 0);
    for (int it = 0; it < 16; ++it) {
        const int cur = it & 1;
        __syncthreads();
        if (it < 15) PROJ_STAGE(cur ^ 1, it + 1);
#pragma unroll
        for (int h = 0; h < 2; ++h) {
            short8 af[2], bf[4];
#pragma unroll
            for (int i = 0; i < 2; ++i)
                af[i] = *(const short8*)&Bs[cur][h][offPM[i]];
#pragma unroll
            for (int j = 0; j < 4; ++j)
                bf[j] = *(const short8*)&As[cur][h][offPN[j]];
#pragma unroll
            for (int i = 0; i < 2; ++i)
#pragma unroll
                for (int j = 0; j < 4; ++j)
                    acc[i][j] = MFMA16(af[i], bf[j], acc[i][j]);  // D[m=col][n=row]
        }
    }
#undef PROJ_STAGE

#pragma unroll
    for (int i = 0; i < 2; ++i) {
        const int col0 = bn + wr * 32 + i * 16 + quad * 4;
        const float4 bp = *(const float4*)(bias + col0);
#pragma unroll
        for (int j = 0; j < 4; ++j) {
            const int row = bm + wc * 64 + j * 16 + l15;
            float4 o;
            o.x = acc[i][j][0] + bp.x;
            o.y = acc[i][j][1] + bp.y;
            o.z = acc[i][j][2] + bp.z;
            o.w = acc[i][j][3] + bp.w;
            *(float4*)(out + (size_t)row * E_ + col0) = o;
        }
    }
}

// ---------------------------------------------------------------------------
extern "C" void kernel_launch(void* const* d_in, const int* in_sizes, int n_in,
                              void* d_out, int out_size, void* d_ws, size_t ws_size,
                              hipStream_t stream)
{
    const float* x      = (const float*)d_in[0];
    const float* w_qkv  = (const float*)d_in[1];
    const float* b_qkv  = (const float*)d_in[2];
    const float* w_proj = (const float*)d_in[3];
    const float* b_proj = (const float*)d_in[4];
    float* out = (float*)d_out;

    // ws (bf16 elems): xb 4M | wqp 3M | wpb 1M | Q 4M | K 4M | VT 4M | CTX 4M
    // then bias_perm (3072 fp32)
    unsigned short* xb  = (unsigned short*)d_ws;
    unsigned short* wqp = xb  + 4194304;
    unsigned short* wpb = wqp + 3145728;
    unsigned short* Q   = wpb + 1048576;
    unsigned short* K   = Q   + 4194304;
    unsigned short* VT  = K   + 4194304;
    unsigned short* CTX = VT  + 4194304;
    float* bias_perm    = (float*)(CTX + 4194304);

    dim3 blk(256);
    convert_kernel<<<dim3(4097), blk, 0, stream>>>(
        x, w_qkv, w_proj, b_qkv, xb, wqp, wpb, bias_perm);

    qkv_kernel<<<dim3(24, 32), blk, 0, stream>>>(xb, wqp, bias_perm, Q, K, VT);

    attn_kernel<<<dim3(B_ * H_ * (N_ / 64)), blk, 0, stream>>>(Q, K, VT, CTX);

    proj_kernel<<<dim3(16, 32), blk, 0, stream>>>(CTX, wpb, b_proj, out);
}

// Round 12
// 188.483 us; speedup vs baseline: 1.0304x; 1.0060x over previous
//
#include <hip/hip_runtime.h>
#include <hip/hip_bf16.h>
#include <math.h>

#define B_   2
#define N_   2048
#define E_   1024
#define H_   16
#define D_   64
#define E3_  3072
#define M_   (B_ * N_)   // 4096

// log2(e)/8 folded into Q so softmax inner loop is a bare exp2
#define QSCALE 0.18033688011112042f

using short8  = __attribute__((ext_vector_type(8))) short;
using short4v = __attribute__((ext_vector_type(4))) short;
using f32x4   = __attribute__((ext_vector_type(4))) float;
using uint2v  = __attribute__((ext_vector_type(2))) unsigned int;
using uint4v  = __attribute__((ext_vector_type(4))) unsigned int;

#define MFMA16(a, b, c)    __builtin_amdgcn_mfma_f32_16x16x32_bf16((a), (b), (c), 0, 0, 0)

__device__ __forceinline__ unsigned short f2bf(float f) {
    __hip_bfloat16 h = __float2bfloat16(f);
    return __builtin_bit_cast(unsigned short, h);
}

__device__ __forceinline__ float fast_exp2(float x) {
#if __has_builtin(__builtin_amdgcn_exp2f)
    return __builtin_amdgcn_exp2f(x);
#else
    return exp2f(x);
#endif
}

// pack two floats to a bf16x2 dword.  gfx950 has v_cvt_pk_bf16_f32 (1 op,
// RNE); fallback = round-half-up bit trick (3 ops).
__device__ __forceinline__ unsigned int pack_bf16_2(float lo, float hi) {
#if __has_builtin(__builtin_amdgcn_cvt_pk_bf16_f32)
    auto pk = __builtin_amdgcn_cvt_pk_bf16_f32(lo, hi);
    return *(const unsigned int*)&pk;
#else
    unsigned int ulo = __builtin_bit_cast(unsigned int, lo) + 0x8000u;
    unsigned int uhi = __builtin_bit_cast(unsigned int, hi) + 0x8000u;
#if __has_builtin(__builtin_amdgcn_perm)
    return __builtin_amdgcn_perm(uhi, ulo, 0x07060302u);
#else
    return (uhi & 0xFFFF0000u) | (ulo >> 16);
#endif
#endif
}

// async global->LDS, 16B per lane
__device__ __forceinline__ void gl16(const void* g, void* l) {
    __builtin_amdgcn_global_load_lds(
        (__attribute__((address_space(1))) const void*)g,
        (__attribute__((address_space(3))) void*)l, 16, 0, 0);
}

// ---------------------------------------------------------------------------
// Kernel 0: fp32->bf16: x->xb; w_qkv row-permuted (slot s = c*1024+h*64+d) ->
// wqp; w_proj->wpb.  Block 4096: permuted (+Q-prescaled) bias -> bias_perm.
// ---------------------------------------------------------------------------
__global__ __launch_bounds__(256) void convert_kernel(
    const float* __restrict__ x, const float* __restrict__ wq,
    const float* __restrict__ wp, const float* __restrict__ b_qkv,
    unsigned short* __restrict__ xb, unsigned short* __restrict__ wqp,
    unsigned short* __restrict__ wpb, float* __restrict__ bias_perm)
{
    if (blockIdx.x == 4096) {
        for (int q = threadIdx.x; q < E3_; q += 256) {
            const int c = q >> 10, rem = q & 1023;
            const int h = rem >> 6, d = rem & 63;
            float v = b_qkv[h * 192 + d * 3 + c];
            if (c == 0) v *= QSCALE;
            bias_perm[q] = v;
        }
        return;
    }
    const int o = (blockIdx.x * 256 + threadIdx.x) * 8;
    const float* src;
    unsigned short* dst;
    if (o < 4194304) {                     // x: 4M
        src = x + o; dst = xb + o;
    } else if (o < 7340032) {              // w_qkv permuted: 3M
        const int oo = o - 4194304;
        const int s = oo >> 10, k = oo & 1023;
        const int c = s >> 10, rem = s & 1023;
        const int h = rem >> 6, d = rem & 63;
        src = wq + (size_t)(h * 192 + d * 3 + c) * E_ + k;
        dst = wqp + oo;
    } else {                               // w_proj: 1M
        const int oo = o - 7340032;
        src = wp + oo; dst = wpb + oo;
    }
    float4 a = *(const float4*)src;
    float4 b = *(const float4*)(src + 4);
    uint2v p0, p1;
    p0.x = pack_bf16_2(a.x, a.y); p0.y = pack_bf16_2(a.z, a.w);
    p1.x = pack_bf16_2(b.x, b.y); p1.y = pack_bf16_2(b.z, b.w);
    *(uint2v*)dst = p0;
    *(uint2v*)(dst + 4) = p1;
}

#define GEMM_PROLOG                                                          \
    const int t    = threadIdx.x;                                            \
    const int wv   = t >> 6, lane = t & 63;                                  \
    const int quad = lane >> 4, l15 = lane & 15;                             \
    const int wr   = wv & 1, wc = wv >> 1;                                   \
    f32x4 acc[4][4];                                                         \
    _Pragma("unroll")                                                        \
    for (int i = 0; i < 4; ++i)                                              \
        _Pragma("unroll")                                                    \
        for (int j = 0; j < 4; ++j) acc[i][j] = (f32x4){0.f, 0.f, 0.f, 0.f};

// ---------------------------------------------------------------------------
// Kernel 1: merged qkv GEMM over all 3072 output slots (grid 24 x 32).
// 128x128 tile, BK=32, 4 waves (2x2), global_load_lds(16B), XOR-swizzled
// LDS, 2-buffer ping-pong + __syncthreads (R6-verified).  BK stays 32:
// BK=64 would need 64KB LDS -> 2 blocks/CU vs the grid's 3/CU (m132 trap).
// r13: XCD-aware block swizzle (T1), 768 = 8*96 bijective.
// r14: V-branch stores VT key-paired (slot gi*8+hi*4+j) -> attn PV at K=32.
// r17: staging addresses hoisted to per-lane base pointers; fragment LDS
// offsets precomputed.
// ---------------------------------------------------------------------------
__global__ __launch_bounds__(256) void qkv_kernel(
    const unsigned short* __restrict__ A, const unsigned short* __restrict__ Bm,
    const float* __restrict__ bias_perm,
    unsigned short* __restrict__ Q, unsigned short* __restrict__ K,
    unsigned short* __restrict__ VT)
{
    __shared__ __attribute__((aligned(16))) unsigned short As[2][128 * 32];
    __shared__ __attribute__((aligned(16))) unsigned short Bs[2][128 * 32];
    GEMM_PROLOG
    // XCD swizzle: HW round-robins original linear id across 8 XCDs.
    const int lid = blockIdx.x + 24 * blockIdx.y;        // 0..767
    const int swz = (lid & 7) * 96 + (lid >> 3);         // bijective (768=8*96)
    const int bx  = swz % 24, by = swz / 24;
    const int bm = by * 128;   // token rows
    const int bn = bx * 128;   // s slots
    const int c  = bn >> 10;   // 0=Q,1=K,2=V (uniform per block)

    // --- r17 hoisted staging bases (identical address algebra to r13) ---
    const int chunk0 = wv * 128 + lane;
    const int row0   = chunk0 >> 2;
    const int g0     = ((chunk0 & 3) ^ ((row0 >> 1) & 3)) * 8;
    const int chunk1 = chunk0 + 64;
    const int row1   = chunk1 >> 2;
    const int g1     = ((chunk1 & 3) ^ ((row1 >> 1) & 3)) * 8;
    const unsigned short* aS0 = A  + (size_t)(bm + row0) * E_ + g0;
    const unsigned short* aS1 = A  + (size_t)(bm + row1) * E_ + g1;
    const unsigned short* bS0 = Bm + (size_t)(bn + row0) * E_ + g0;
    const unsigned short* bS1 = Bm + (size_t)(bn + row1) * E_ + g1;
    const int ldsOff0 = wv * 1024;        // shorts: (wv*128+ 0)*8
    const int ldsOff1 = wv * 1024 + 512;  // shorts: (wv*128+64)*8

#define QKV_STAGE(buf, k0)                                                   \
    {                                                                        \
        gl16(aS0 + (k0), &As[buf][ldsOff0]);                                 \
        gl16(bS0 + (k0), &Bs[buf][ldsOff0]);                                 \
        gl16(aS1 + (k0), &As[buf][ldsOff1]);                                 \
        gl16(bS1 + (k0), &Bs[buf][ldsOff1]);                                 \
    }

    // --- r17 hoisted fragment offsets (loop-invariant) ---
    const int sw = (l15 >> 1) & 3;
    int offM[4], offN[4];
#pragma unroll
    for (int i = 0; i < 4; ++i) {
        offM[i] = (wr * 64 + i * 16 + l15) * 32 + ((quad ^ sw) * 8);
        offN[i] = (wc * 64 + i * 16 + l15) * 32 + ((quad ^ sw) * 8);
    }

    QKV_STAGE(0, 0);
    if (c < 2) {
        for (int it = 0; it < 32; ++it) {
            const int cur = it & 1;
            __syncthreads();
            if (it < 31) QKV_STAGE(cur ^ 1, (it + 1) * 32);
            short8 af[4], bf[4];
#pragma unroll
            for (int i = 0; i < 4; ++i) {
                af[i] = *(const short8*)&Bs[cur][offM[i]];   // m = s slots
                bf[i] = *(const short8*)&As[cur][offN[i]];   // n = tokens
            }
#pragma unroll
            for (int i = 0; i < 4; ++i)
#pragma unroll
                for (int j = 0; j < 4; ++j)
                    acc[i][j] = MFMA16(af[i], bf[j], acc[i][j]);  // D[m=s][n=tok]
        }
        const float scale = (c == 0) ? QSCALE : 1.0f;
        unsigned short* dst0 = (c == 0) ? Q : K;
#pragma unroll
        for (int i = 0; i < 4; ++i) {
            const int s0 = bn + wr * 64 + i * 16 + quad * 4;
            const int h  = (s0 >> 6) & 15;
            const int d0 = s0 & 63;
            const float4 bq = *(const float4*)(bias_perm + s0);
#pragma unroll
            for (int j = 0; j < 4; ++j) {
                const int row = bm + wc * 64 + j * 16 + l15;
                const int b   = row >> 11, n = row & (N_ - 1);
                const float v0 = fmaf(acc[i][j][0], scale, bq.x);
                const float v1 = fmaf(acc[i][j][1], scale, bq.y);
                const float v2 = fmaf(acc[i][j][2], scale, bq.z);
                const float v3 = fmaf(acc[i][j][3], scale, bq.w);
                uint2v pk;
                pk.x = pack_bf16_2(v0, v1);
                pk.y = pack_bf16_2(v2, v3);
                *(uint2v*)(dst0 + (((size_t)b * H_ + h) * N_ + n) * D_ + d0) = pk;
            }
        }
    } else {
        for (int it = 0; it < 32; ++it) {
            const int cur = it & 1;
            __syncthreads();
            if (it < 31) QKV_STAGE(cur ^ 1, (it + 1) * 32);
            short8 af[4], bf[4];
#pragma unroll
            for (int i = 0; i < 4; ++i) {
                af[i] = *(const short8*)&As[cur][offM[i]];   // m = tokens
                bf[i] = *(const short8*)&Bs[cur][offN[i]];   // n = s slots
            }
#pragma unroll
            for (int i = 0; i < 4; ++i)
#pragma unroll
                for (int j = 0; j < 4; ++j)
                    acc[i][j] = MFMA16(af[i], bf[j], acc[i][j]);  // D[m=tok][n=s]
        }
#pragma unroll
        for (int j = 0; j < 4; ++j) {
            const int s = bn + wc * 64 + j * 16 + l15;
            const int h = (s >> 6) & 15, d = s & 63;
            const float bv = bias_perm[s];
#pragma unroll
            for (int i = 0; i < 4; ++i) {
                const int row0v = bm + wr * 64 + i * 16 + quad * 4;
                const int b     = row0v >> 11, n0 = row0v & (N_ - 1);
                // r14 key-pair permutation (bijective on 4-aligned groups):
                // np = (n0 & ~31) | gi*8 + hi*4, gi = (n0>>2)&3, hi = (n0>>4)&1
                const int np = (n0 & ~31) | ((((n0 >> 2) & 3) << 3) + (((n0 >> 4) & 1) << 2));
                uint2v pk;
                pk.x = pack_bf16_2(acc[i][j][0] + bv, acc[i][j][1] + bv);
                pk.y = pack_bf16_2(acc[i][j][2] + bv, acc[i][j][3] + bv);
                *(uint2v*)(VT + (((size_t)b * H_ + h) * D_ + d) * N_ + np) = pk;
            }
        }
    }
#undef QKV_STAGE
}

// ---------------------------------------------------------------------------
// Kernel 2: flash attention.
// r21: QBLK=128, 8 waves (512 thr), hybrid partition wq∈0..3 (q-rows
// wq*32..+32), wk∈0..1 (keys wk*32..+32) — instruction-identical per-wave
// kt body to the verified r15 kernel (same slot maps, same MFMA stream,
// same 32-key split per wave), so output is BIT-IDENTICAL.  Motivation
// (R11 finding): FETCH dropped 5.6x with dur flat -> wall is per-block-kt
// overhead (stage issue, vmcnt drain, barrier skew).  At QBLK=128 the same
// 16 waves/CU are organized as 2 blocks instead of 4: per-CU gl16 count
// and barrier instances halve, matrix/VALU work unchanged.
// Grid 512 = 8*64 bijective XCD swizzle (XCD x owns bh [4x,4x+4)).
// Staging: 512 threads cover the 8KB K-tile + 8KB V-tile with exactly one
// gl16 each (cch = t, same XOR formula).
// Epilogue: identical structure; red = 4*2048 floats = exactly the 32KB
// pool; lsumBuf [2][128].
// r20 setprio kept.  PV/lsum at K=32 (r15), hoisted addressing (r17).
// ---------------------------------------------------------------------------
__global__ __launch_bounds__(512, 4) void attn_kernel(
    const unsigned short* __restrict__ Q, const unsigned short* __restrict__ K,
    const unsigned short* __restrict__ VT, unsigned short* __restrict__ CTX)
{
    __shared__ __attribute__((aligned(16))) unsigned short pool[16384]; // Ks[2]|Vs[2]
    __shared__ float lsumBuf[2][128];   // [wk][q]

    const int t    = threadIdx.x;
    const int wv   = t >> 6, lane = t & 63;
    const int quad = lane >> 4, l15 = lane & 15;
    const int wq   = wv & 3, wk = wv >> 2;
    // r21: XCD-aware bijective remap (512 = 8*64)
    const int lid  = blockIdx.x;
    const int swzb = (lid & 7) * 64 + (lid >> 3);
    const int qt   = swzb & 15;   // N/128 q-tiles
    const int bh   = swzb >> 4;

    const unsigned short* Kp = K + (size_t)bh * N_ * D_;
    const unsigned short* Vp = VT + (size_t)bh * D_ * N_;

    // Q B-frags for this wave's 2 q-subtiles (q rows qt*128 + wq*32 + s*16)
    short8 qf[2][2];
#pragma unroll
    for (int s = 0; s < 2; ++s) {
        const unsigned short* Qp =
            Q + ((size_t)bh * N_ + qt * 128 + (wq * 2 + s) * 16 + l15) * D_;
        qf[s][0] = *(const short8*)(Qp + quad * 8);
        qf[s][1] = *(const short8*)(Qp + 32 + quad * 8);
    }

    // --- staging bases: 512 threads, one 16B chunk each (cch = t) ---
    const int srow = t >> 3;
    const int sgc  = ((t & 7) ^ (srow & 7)) * 8;
    const unsigned short* kS = Kp + (size_t)srow * D_ + sgc;
    const unsigned short* vS = Vp + (size_t)srow * N_ + sgc;
    const int aOff = wv * 512;   // shorts; lane*16B auto-appended by gl16

#define ATTN_STAGE(buf, kt)                                                  \
    {                                                                        \
        gl16(kS + (kt) * (64 * D_), &pool[(buf) * 4096 + aOff]);             \
        gl16(vS + (kt) * 64,        &pool[8192 + (buf) * 4096 + aOff]);      \
    }

    // --- hoisted inner LDS read offsets (loop-invariant) ---
    const int koff0 = (quad ^ (l15 & 7)) * 8;
    const int koff1 = ((4 + quad) ^ (l15 & 7)) * 8;
    const int vs128 = ((wk * 4 + quad) ^ (l15 & 7)) * 8;
    int kOff0[2], kOff1[2], vOff[4];
#pragma unroll
    for (int kb = 0; kb < 2; ++kb) {
        const int krow = (wk * 32 + kb * 16 + l15) * 64;
        kOff0[kb] = krow + koff0;
        kOff1[kb] = krow + koff1;
    }
#pragma unroll
    for (int nt = 0; nt < 4; ++nt)
        vOff[nt] = (nt * 16 + l15) * 64 + vs128;

    // bf16 1.0 x8 for the l = P.1 MFMA (K=32)
    short8 ones8;
#pragma unroll
    for (int i = 0; i < 8; ++i) ones8[i] = (short)0x3F80;

    f32x4 O[2][4];   // [q-subtile][nt] partial over this wave's 32 keys
#pragma unroll
    for (int s = 0; s < 2; ++s)
#pragma unroll
        for (int nt = 0; nt < 4; ++nt) O[s][nt] = (f32x4){0.f, 0.f, 0.f, 0.f};
    f32x4 Lacc[2] = {{0.f, 0.f, 0.f, 0.f}, {0.f, 0.f, 0.f, 0.f}};

    ATTN_STAGE(0, 0);

    for (int kt = 0; kt < 32; ++kt) {
        const int cur = kt & 1;
        __syncthreads();
        if (kt < 31) ATTN_STAGE(cur ^ 1, kt + 1);

        const unsigned short* Kc = pool + cur * 4096;
        const unsigned short* Vc = pool + 8192 + cur * 4096;

        // S^T per key-group kb (16 keys) x q-subtile s
        f32x4 st[2][2];
#pragma unroll
        for (int kb = 0; kb < 2; ++kb) {
            const short8 kf0 = *(const short8*)&Kc[kOff0[kb]];
            const short8 kf1 = *(const short8*)&Kc[kOff1[kb]];
#pragma unroll
            for (int s = 0; s < 2; ++s) {
                st[kb][s] = (f32x4){0.f, 0.f, 0.f, 0.f};
                st[kb][s] = MFMA16(kf0, qf[s][0], st[kb][s]);
                st[kb][s] = MFMA16(kf1, qf[s][1], st[kb][s]);
            }
        }

        // softmax numerator: p = exp2(s), packed straight into the K=32
        // A-operand slot order (= r14 VT slot order kappa).
        short8 pa8[2];
#pragma unroll
        for (int s = 0; s < 2; ++s) {
            uint4v u;
            u.x = pack_bf16_2(fast_exp2(st[0][s][0]), fast_exp2(st[0][s][1]));
            u.y = pack_bf16_2(fast_exp2(st[0][s][2]), fast_exp2(st[0][s][3]));
            u.z = pack_bf16_2(fast_exp2(st[1][s][0]), fast_exp2(st[1][s][1]));
            u.w = pack_bf16_2(fast_exp2(st[1][s][2]), fast_exp2(st[1][s][3]));
            pa8[s] = __builtin_bit_cast(short8, u);
        }

        // prioritize this wave through the pure-MFMA stretch (T5)
        __builtin_amdgcn_s_setprio(1);

        // l partials via MFMA (K=32): Lacc[s] += P[s] . 1
#pragma unroll
        for (int s = 0; s < 2; ++s)
            Lacc[s] = MFMA16(pa8[s], ones8, Lacc[s]);

        // PV (K=32): O[s][nt] += P[s] . V(all 32 keys of this wave)
#pragma unroll
        for (int nt = 0; nt < 4; ++nt) {
            const short8 v8 = *(const short8*)&Vc[vOff[nt]];
#pragma unroll
            for (int s = 0; s < 2; ++s)
                O[s][nt] = MFMA16(pa8[s], v8, O[s][nt]);
        }

        __builtin_amdgcn_s_setprio(0);
    }
#undef ATTN_STAGE

    // Lacc D-layout: row q_local = quad*4+g, all 16 cols identical -> lane
    // l15==0 of each quad publishes its 4 q rows.
    if (l15 == 0) {
#pragma unroll
        for (int s = 0; s < 2; ++s)
#pragma unroll
            for (int g = 0; g < 4; ++g)
                lsumBuf[wk][wq * 32 + s * 16 + quad * 4 + g] = Lacc[s][g];
    }
    __syncthreads();   // tile reads done (pool reusable) + lsumBuf visible

    // O D-layout: q = quad*4+g (row), d = nt*16 + l15 (col)
    float* red = (float*)pool;   // 8192 floats = 32KB; [wq][qsub 0..31][d]
    if (wk == 1) {
#pragma unroll
        for (int s = 0; s < 2; ++s)
#pragma unroll
            for (int nt = 0; nt < 4; ++nt)
#pragma unroll
                for (int g = 0; g < 4; ++g)
                    red[wq * 2048 + (s * 16 + quad * 4 + g) * 64 + nt * 16 + l15] =
                        O[s][nt][g];
    }
    __syncthreads();

    if (wk == 0) {
        const int b = bh >> 4, h = bh & 15;
#pragma unroll
        for (int s = 0; s < 2; ++s) {
            float inv[4];
#pragma unroll
            for (int g = 0; g < 4; ++g) {
                const int q = wq * 32 + s * 16 + quad * 4 + g;
                inv[g] = 1.0f / (lsumBuf[0][q] + lsumBuf[1][q]);
            }
#pragma unroll
            for (int nt = 0; nt < 4; ++nt) {
#pragma unroll
                for (int g = 0; g < 4; ++g) {
                    const float o = O[s][nt][g] +
                        red[wq * 2048 + (s * 16 + quad * 4 + g) * 64 + nt * 16 + l15];
                    const int qrow = qt * 128 + wq * 32 + s * 16 + quad * 4 + g;
                    CTX[((size_t)b * N_ + qrow) * E_ + h * D_ + nt * 16 + l15] =
                        f2bf(o * inv[g]);
                }
            }
        }
    }
}

// ---------------------------------------------------------------------------
// Kernel 3: out = ctx @ w_proj^T + b_proj.  128(M) x 64(N) tiles -> 512
// blocks = 2/CU.  C^T orientation -> float4 stores.
// r13: XCD-aware block swizzle (T1), 512 = 8*64 bijective.
// r17: staging bases + fragment offsets hoisted.
// r19: BK=64 via paired 32-wide half-buffers (16 iters, bit-exact).
// ---------------------------------------------------------------------------
__global__ __launch_bounds__(256) void proj_kernel(
    const unsigned short* __restrict__ A, const unsigned short* __restrict__ Bm,
    const float* __restrict__ bias, float* __restrict__ out)
{
    __shared__ __attribute__((aligned(16))) unsigned short As[2][2][128 * 32];
    __shared__ __attribute__((aligned(16))) unsigned short Bs[2][2][64 * 32];
    const int t    = threadIdx.x;
    const int wv   = t >> 6, lane = t & 63;
    const int quad = lane >> 4, l15 = lane & 15;
    const int wr   = wv & 1, wc = wv >> 1;
    const int lid  = blockIdx.x + 16 * blockIdx.y;       // 0..511
    const int swz  = (lid & 7) * 64 + (lid >> 3);        // bijective (512=8*64)
    const int bx   = swz & 15, by = swz >> 4;
    const int bm   = by * 128;   // ctx rows
    const int bn   = bx * 64;    // out cols

    f32x4 acc[2][4];
#pragma unroll
    for (int i = 0; i < 2; ++i)
#pragma unroll
        for (int j = 0; j < 4; ++j) acc[i][j] = (f32x4){0.f, 0.f, 0.f, 0.f};

    // --- r17 hoisted staging bases ---
    const int pc0 = wv * 128 + lane, pr0 = pc0 >> 2;
    const int pg0 = ((pc0 & 3) ^ ((pr0 >> 1) & 3)) * 8;
    const int pc1 = pc0 + 64, pr1 = pc1 >> 2;
    const int pg1 = ((pc1 & 3) ^ ((pr1 >> 1) & 3)) * 8;
    const int pcB = wv * 64 + lane, prB = pcB >> 2;
    const int pgB = ((pcB & 3) ^ ((prB >> 1) & 3)) * 8;
    const unsigned short* aS0 = A  + (size_t)(bm + pr0) * E_ + pg0;
    const unsigned short* aS1 = A  + (size_t)(bm + pr1) * E_ + pg1;
    const unsigned short* bS  = Bm + (size_t)(bn + prB) * E_ + pgB;
    const int ldsA0 = wv * 1024, ldsA1 = wv * 1024 + 512, ldsB0 = wv * 512;

// r19: stage BOTH 32-wide halves of K-pair it2 (K cols [it2*64, it2*64+64))
#define PROJ_STAGE(buf, it2)                                                 \
    {                                                                        \
        gl16(aS0 + (it2) * 64,      &As[buf][0][ldsA0]);                     \
        gl16(aS1 + (it2) * 64,      &As[buf][0][ldsA1]);                     \
        gl16(bS  + (it2) * 64,      &Bs[buf][0][ldsB0]);                     \
        gl16(aS0 + (it2) * 64 + 32, &As[buf][1][ldsA0]);                     \
        gl16(aS1 + (it2) * 64 + 32, &As[buf][1][ldsA1]);                     \
        gl16(bS  + (it2) * 64 + 32, &Bs[buf][1][ldsB0]);                     \
    }

    // --- r17 hoisted fragment offsets ---
    const int sw = (l15 >> 1) & 3;
    int offPM[2], offPN[4];
#pragma unroll
    for (int i = 0; i < 2; ++i)
        offPM[i] = (wr * 32 + i * 16 + l15) * 32 + ((quad ^ sw) * 8);
#pragma unroll
    for (int j = 0; j < 4; ++j)
        offPN[j] = (wc * 64 + j * 16 + l15) * 32 + ((quad ^ sw) * 8);

    PROJ_STAGE(0, 0);
    for (int it = 0; it < 16; ++it) {
        const int cur = it & 1;
        __syncthreads();
        if (it < 15) PROJ_STAGE(cur ^ 1, it + 1);
#pragma unroll
        for (int h = 0; h < 2; ++h) {
            short8 af[2], bf[4];
#pragma unroll
            for (int i = 0; i < 2; ++i)
                af[i] = *(const short8*)&Bs[cur][h][offPM[i]];
#pragma unroll
            for (int j = 0; j < 4; ++j)
                bf[j] = *(const short8*)&As[cur][h][offPN[j]];
#pragma unroll
            for (int i = 0; i < 2; ++i)
#pragma unroll
                for (int j = 0; j < 4; ++j)
                    acc[i][j] = MFMA16(af[i], bf[j], acc[i][j]);  // D[m=col][n=row]
        }
    }
#undef PROJ_STAGE

#pragma unroll
    for (int i = 0; i < 2; ++i) {
        const int col0 = bn + wr * 32 + i * 16 + quad * 4;
        const float4 bp = *(const float4*)(bias + col0);
#pragma unroll
        for (int j = 0; j < 4; ++j) {
            const int row = bm + wc * 64 + j * 16 + l15;
            float4 o;
            o.x = acc[i][j][0] + bp.x;
            o.y = acc[i][j][1] + bp.y;
            o.z = acc[i][j][2] + bp.z;
            o.w = acc[i][j][3] + bp.w;
            *(float4*)(out + (size_t)row * E_ + col0) = o;
        }
    }
}

// ---------------------------------------------------------------------------
extern "C" void kernel_launch(void* const* d_in, const int* in_sizes, int n_in,
                              void* d_out, int out_size, void* d_ws, size_t ws_size,
                              hipStream_t stream)
{
    const float* x      = (const float*)d_in[0];
    const float* w_qkv  = (const float*)d_in[1];
    const float* b_qkv  = (const float*)d_in[2];
    const float* w_proj = (const float*)d_in[3];
    const float* b_proj = (const float*)d_in[4];
    float* out = (float*)d_out;

    // ws (bf16 elems): xb 4M | wqp 3M | wpb 1M | Q 4M | K 4M | VT 4M | CTX 4M
    // then bias_perm (3072 fp32)
    unsigned short* xb  = (unsigned short*)d_ws;
    unsigned short* wqp = xb  + 4194304;
    unsigned short* wpb = wqp + 3145728;
    unsigned short* Q   = wpb + 1048576;
    unsigned short* K   = Q   + 4194304;
    unsigned short* VT  = K   + 4194304;
    unsigned short* CTX = VT  + 4194304;
    float* bias_perm    = (float*)(CTX + 4194304);

    dim3 blk(256);
    convert_kernel<<<dim3(4097), blk, 0, stream>>>(
        x, w_qkv, w_proj, b_qkv, xb, wqp, wpb, bias_perm);

    qkv_kernel<<<dim3(24, 32), blk, 0, stream>>>(xb, wqp, bias_perm, Q, K, VT);

    attn_kernel<<<dim3(B_ * H_ * (N_ / 128)), dim3(512), 0, stream>>>(Q, K, VT, CTX);

    proj_kernel<<<dim3(16, 32), blk, 0, stream>>>(CTX, wpb, b_proj, out);
}

// Round 13
// 177.540 us; speedup vs baseline: 1.0939x; 1.0616x over previous
//
#include <hip/hip_runtime.h>
#include <hip/hip_bf16.h>
#include <math.h>

#define B_   2
#define N_   2048
#define E_   1024
#define H_   16
#define D_   64
#define E3_  3072
#define M_   (B_ * N_)   // 4096

// log2(e)/8 folded into Q so softmax inner loop is a bare exp2
#define QSCALE 0.18033688011112042f

using short8  = __attribute__((ext_vector_type(8))) short;
using short4v = __attribute__((ext_vector_type(4))) short;
using f32x4   = __attribute__((ext_vector_type(4))) float;
using uint2v  = __attribute__((ext_vector_type(2))) unsigned int;
using uint4v  = __attribute__((ext_vector_type(4))) unsigned int;

#define MFMA16(a, b, c)    __builtin_amdgcn_mfma_f32_16x16x32_bf16((a), (b), (c), 0, 0, 0)

__device__ __forceinline__ unsigned short f2bf(float f) {
    __hip_bfloat16 h = __float2bfloat16(f);
    return __builtin_bit_cast(unsigned short, h);
}

__device__ __forceinline__ float fast_exp2(float x) {
#if __has_builtin(__builtin_amdgcn_exp2f)
    return __builtin_amdgcn_exp2f(x);
#else
    return exp2f(x);
#endif
}

// pack two floats to a bf16x2 dword.  gfx950 has v_cvt_pk_bf16_f32 (1 op,
// RNE); fallback = round-half-up bit trick (3 ops).
__device__ __forceinline__ unsigned int pack_bf16_2(float lo, float hi) {
#if __has_builtin(__builtin_amdgcn_cvt_pk_bf16_f32)
    auto pk = __builtin_amdgcn_cvt_pk_bf16_f32(lo, hi);
    return *(const unsigned int*)&pk;
#else
    unsigned int ulo = __builtin_bit_cast(unsigned int, lo) + 0x8000u;
    unsigned int uhi = __builtin_bit_cast(unsigned int, hi) + 0x8000u;
#if __has_builtin(__builtin_amdgcn_perm)
    return __builtin_amdgcn_perm(uhi, ulo, 0x07060302u);
#else
    return (uhi & 0xFFFF0000u) | (ulo >> 16);
#endif
#endif
}

// async global->LDS, 16B per lane
__device__ __forceinline__ void gl16(const void* g, void* l) {
    __builtin_amdgcn_global_load_lds(
        (__attribute__((address_space(1))) const void*)g,
        (__attribute__((address_space(3))) void*)l, 16, 0, 0);
}

// ---------------------------------------------------------------------------
// Kernel 0: fp32->bf16: x->xb; w_qkv row-permuted (slot s = c*1024+h*64+d) ->
// wqp; w_proj->wpb.  Block 4096: permuted (+Q-prescaled) bias -> bias_perm.
// ---------------------------------------------------------------------------
__global__ __launch_bounds__(256) void convert_kernel(
    const float* __restrict__ x, const float* __restrict__ wq,
    const float* __restrict__ wp, const float* __restrict__ b_qkv,
    unsigned short* __restrict__ xb, unsigned short* __restrict__ wqp,
    unsigned short* __restrict__ wpb, float* __restrict__ bias_perm)
{
    if (blockIdx.x == 4096) {
        for (int q = threadIdx.x; q < E3_; q += 256) {
            const int c = q >> 10, rem = q & 1023;
            const int h = rem >> 6, d = rem & 63;
            float v = b_qkv[h * 192 + d * 3 + c];
            if (c == 0) v *= QSCALE;
            bias_perm[q] = v;
        }
        return;
    }
    const int o = (blockIdx.x * 256 + threadIdx.x) * 8;
    const float* src;
    unsigned short* dst;
    if (o < 4194304) {                     // x: 4M
        src = x + o; dst = xb + o;
    } else if (o < 7340032) {              // w_qkv permuted: 3M
        const int oo = o - 4194304;
        const int s = oo >> 10, k = oo & 1023;
        const int c = s >> 10, rem = s & 1023;
        const int h = rem >> 6, d = rem & 63;
        src = wq + (size_t)(h * 192 + d * 3 + c) * E_ + k;
        dst = wqp + oo;
    } else {                               // w_proj: 1M
        const int oo = o - 7340032;
        src = wp + oo; dst = wpb + oo;
    }
    float4 a = *(const float4*)src;
    float4 b = *(const float4*)(src + 4);
    uint2v p0, p1;
    p0.x = pack_bf16_2(a.x, a.y); p0.y = pack_bf16_2(a.z, a.w);
    p1.x = pack_bf16_2(b.x, b.y); p1.y = pack_bf16_2(b.z, b.w);
    *(uint2v*)dst = p0;
    *(uint2v*)(dst + 4) = p1;
}

#define GEMM_PROLOG                                                          \
    const int t    = threadIdx.x;                                            \
    const int wv   = t >> 6, lane = t & 63;                                  \
    const int quad = lane >> 4, l15 = lane & 15;                             \
    const int wr   = wv & 1, wc = wv >> 1;                                   \
    f32x4 acc[4][4];                                                         \
    _Pragma("unroll")                                                        \
    for (int i = 0; i < 4; ++i)                                              \
        _Pragma("unroll")                                                    \
        for (int j = 0; j < 4; ++j) acc[i][j] = (f32x4){0.f, 0.f, 0.f, 0.f};

// counted-vmcnt barrier (R7-verified protocol): wait for all but the
// newest `n` of THIS wave's VMEM ops, then raw-barrier.  sched_barrier
// pins the following stage below the barrier.
#define PIPE_BARRIER(n)                                                      \
    {                                                                        \
        asm volatile("s_waitcnt vmcnt(" #n ")" ::: "memory");                \
        __builtin_amdgcn_s_barrier();                                        \
        __builtin_amdgcn_sched_barrier(0);                                   \
    }

// ---------------------------------------------------------------------------
// Kernel 1: merged qkv GEMM over all 3072 output slots (grid 24 x 32).
// 128x128 tile, BK=32, 4 waves (2x2), global_load_lds(16B), XOR-swizzled
// LDS.
// r22: 3-BUFFER counted-vmcnt pipeline (48 KB LDS) — depth-2 prefetch with
// vmcnt(4), KEEPING 3 blocks/CU (R7's neutral result used 4 buffers=64KB ->
// 2 blocks/CU + worse FETCH; that confound is removed here).  Per-round the
// old __syncthreads vmcnt(0) serialized stage-drain (~1400cy) against
// compute (~1500cy); counted waits let them overlap.
// Race proof: stage(it+2) writes buf[(it+2)%3] = buf[(it-1)%3]; all waves'
// ds_reads of that buffer completed before their barrier_it arrival
// (lgkmcnt precedes MFMA issue precedes barrier), and gl16s issue only
// after barrier release (all waves arrived).  vmcnt(4): newest outstanding
// at the wait is stage(it+1)'s 4 loads -> stage(it) guaranteed landed.
// r13: XCD swizzle (768 = 8*96 bijective).  r14: VT key-paired store.
// r17: hoisted staging bases + fragment offsets.
// ---------------------------------------------------------------------------
__global__ __launch_bounds__(256) void qkv_kernel(
    const unsigned short* __restrict__ A, const unsigned short* __restrict__ Bm,
    const float* __restrict__ bias_perm,
    unsigned short* __restrict__ Q, unsigned short* __restrict__ K,
    unsigned short* __restrict__ VT)
{
    __shared__ __attribute__((aligned(16))) unsigned short As[3][128 * 32];
    __shared__ __attribute__((aligned(16))) unsigned short Bs[3][128 * 32];
    GEMM_PROLOG
    // XCD swizzle: HW round-robins original linear id across 8 XCDs.
    const int lid = blockIdx.x + 24 * blockIdx.y;        // 0..767
    const int swz = (lid & 7) * 96 + (lid >> 3);         // bijective (768=8*96)
    const int bx  = swz % 24, by = swz / 24;
    const int bm = by * 128;   // token rows
    const int bn = bx * 128;   // s slots
    const int c  = bn >> 10;   // 0=Q,1=K,2=V (uniform per block)

    // --- r17 hoisted staging bases ---
    const int chunk0 = wv * 128 + lane;
    const int row0   = chunk0 >> 2;
    const int g0     = ((chunk0 & 3) ^ ((row0 >> 1) & 3)) * 8;
    const int chunk1 = chunk0 + 64;
    const int row1   = chunk1 >> 2;
    const int g1     = ((chunk1 & 3) ^ ((row1 >> 1) & 3)) * 8;
    const unsigned short* aS0 = A  + (size_t)(bm + row0) * E_ + g0;
    const unsigned short* aS1 = A  + (size_t)(bm + row1) * E_ + g1;
    const unsigned short* bS0 = Bm + (size_t)(bn + row0) * E_ + g0;
    const unsigned short* bS1 = Bm + (size_t)(bn + row1) * E_ + g1;
    const int ldsOff0 = wv * 1024;        // shorts: (wv*128+ 0)*8
    const int ldsOff1 = wv * 1024 + 512;  // shorts: (wv*128+64)*8

#define QKV_STAGE(buf, k0)                                                   \
    {                                                                        \
        gl16(aS0 + (k0), &As[buf][ldsOff0]);                                 \
        gl16(bS0 + (k0), &Bs[buf][ldsOff0]);                                 \
        gl16(aS1 + (k0), &As[buf][ldsOff1]);                                 \
        gl16(bS1 + (k0), &Bs[buf][ldsOff1]);                                 \
    }

    // --- r17 hoisted fragment offsets (loop-invariant) ---
    const int sw = (l15 >> 1) & 3;
    int offM[4], offN[4];
#pragma unroll
    for (int i = 0; i < 4; ++i) {
        offM[i] = (wr * 64 + i * 16 + l15) * 32 + ((quad ^ sw) * 8);
        offN[i] = (wc * 64 + i * 16 + l15) * 32 + ((quad ^ sw) * 8);
    }

    QKV_STAGE(0, 0);
    QKV_STAGE(1, 32);
    int cur = 0, nx2 = 2;   // buf of it, buf of it+2 (rotating mod 3)
    if (c < 2) {
        for (int it = 0; it < 32; ++it) {
            if (it < 31) PIPE_BARRIER(4) else PIPE_BARRIER(0);
            if (it < 30) QKV_STAGE(nx2, (it + 2) * 32);
            short8 af[4], bf[4];
#pragma unroll
            for (int i = 0; i < 4; ++i) {
                af[i] = *(const short8*)&Bs[cur][offM[i]];   // m = s slots
                bf[i] = *(const short8*)&As[cur][offN[i]];   // n = tokens
            }
#pragma unroll
            for (int i = 0; i < 4; ++i)
#pragma unroll
                for (int j = 0; j < 4; ++j)
                    acc[i][j] = MFMA16(af[i], bf[j], acc[i][j]);  // D[m=s][n=tok]
            if (++cur == 3) cur = 0;
            if (++nx2 == 3) nx2 = 0;
        }
        const float scale = (c == 0) ? QSCALE : 1.0f;
        unsigned short* dst0 = (c == 0) ? Q : K;
#pragma unroll
        for (int i = 0; i < 4; ++i) {
            const int s0 = bn + wr * 64 + i * 16 + quad * 4;
            const int h  = (s0 >> 6) & 15;
            const int d0 = s0 & 63;
            const float4 bq = *(const float4*)(bias_perm + s0);
#pragma unroll
            for (int j = 0; j < 4; ++j) {
                const int row = bm + wc * 64 + j * 16 + l15;
                const int b   = row >> 11, n = row & (N_ - 1);
                const float v0 = fmaf(acc[i][j][0], scale, bq.x);
                const float v1 = fmaf(acc[i][j][1], scale, bq.y);
                const float v2 = fmaf(acc[i][j][2], scale, bq.z);
                const float v3 = fmaf(acc[i][j][3], scale, bq.w);
                uint2v pk;
                pk.x = pack_bf16_2(v0, v1);
                pk.y = pack_bf16_2(v2, v3);
                *(uint2v*)(dst0 + (((size_t)b * H_ + h) * N_ + n) * D_ + d0) = pk;
            }
        }
    } else {
        for (int it = 0; it < 32; ++it) {
            if (it < 31) PIPE_BARRIER(4) else PIPE_BARRIER(0);
            if (it < 30) QKV_STAGE(nx2, (it + 2) * 32);
            short8 af[4], bf[4];
#pragma unroll
            for (int i = 0; i < 4; ++i) {
                af[i] = *(const short8*)&As[cur][offM[i]];   // m = tokens
                bf[i] = *(const short8*)&Bs[cur][offN[i]];   // n = s slots
            }
#pragma unroll
            for (int i = 0; i < 4; ++i)
#pragma unroll
                for (int j = 0; j < 4; ++j)
                    acc[i][j] = MFMA16(af[i], bf[j], acc[i][j]);  // D[m=tok][n=s]
            if (++cur == 3) cur = 0;
            if (++nx2 == 3) nx2 = 0;
        }
#pragma unroll
        for (int j = 0; j < 4; ++j) {
            const int s = bn + wc * 64 + j * 16 + l15;
            const int h = (s >> 6) & 15, d = s & 63;
            const float bv = bias_perm[s];
#pragma unroll
            for (int i = 0; i < 4; ++i) {
                const int row0v = bm + wr * 64 + i * 16 + quad * 4;
                const int b     = row0v >> 11, n0 = row0v & (N_ - 1);
                // r14 key-pair permutation (bijective on 4-aligned groups):
                // np = (n0 & ~31) | gi*8 + hi*4, gi = (n0>>2)&3, hi = (n0>>4)&1
                const int np = (n0 & ~31) | ((((n0 >> 2) & 3) << 3) + (((n0 >> 4) & 1) << 2));
                uint2v pk;
                pk.x = pack_bf16_2(acc[i][j][0] + bv, acc[i][j][1] + bv);
                pk.y = pack_bf16_2(acc[i][j][2] + bv, acc[i][j][3] + bv);
                *(uint2v*)(VT + (((size_t)b * H_ + h) * D_ + d) * N_ + np) = pk;
            }
        }
    }
#undef QKV_STAGE
}

// ---------------------------------------------------------------------------
// Kernel 2: flash attention.
// r21: QBLK=128, 8 waves (512 thr), hybrid partition wq∈0..3, wk∈0..1 —
// per-wave kt body instruction-identical to the verified r15 kernel
// (bit-identical output).  Verified: attn dropped below qkv in R12.
// Grid 512 = 8*64 bijective XCD swizzle (XCD x owns bh [4x,4x+4)).
// r20 setprio kept.  PV/lsum at K=32 (r15), hoisted addressing (r17).
// ---------------------------------------------------------------------------
__global__ __launch_bounds__(512, 4) void attn_kernel(
    const unsigned short* __restrict__ Q, const unsigned short* __restrict__ K,
    const unsigned short* __restrict__ VT, unsigned short* __restrict__ CTX)
{
    __shared__ __attribute__((aligned(16))) unsigned short pool[16384]; // Ks[2]|Vs[2]
    __shared__ float lsumBuf[2][128];   // [wk][q]

    const int t    = threadIdx.x;
    const int wv   = t >> 6, lane = t & 63;
    const int quad = lane >> 4, l15 = lane & 15;
    const int wq   = wv & 3, wk = wv >> 2;
    // XCD-aware bijective remap (512 = 8*64)
    const int lid  = blockIdx.x;
    const int swzb = (lid & 7) * 64 + (lid >> 3);
    const int qt   = swzb & 15;   // N/128 q-tiles
    const int bh   = swzb >> 4;

    const unsigned short* Kp = K + (size_t)bh * N_ * D_;
    const unsigned short* Vp = VT + (size_t)bh * D_ * N_;

    // Q B-frags for this wave's 2 q-subtiles (q rows qt*128 + wq*32 + s*16)
    short8 qf[2][2];
#pragma unroll
    for (int s = 0; s < 2; ++s) {
        const unsigned short* Qp =
            Q + ((size_t)bh * N_ + qt * 128 + (wq * 2 + s) * 16 + l15) * D_;
        qf[s][0] = *(const short8*)(Qp + quad * 8);
        qf[s][1] = *(const short8*)(Qp + 32 + quad * 8);
    }

    // --- staging bases: 512 threads, one 16B chunk each (cch = t) ---
    const int srow = t >> 3;
    const int sgc  = ((t & 7) ^ (srow & 7)) * 8;
    const unsigned short* kS = Kp + (size_t)srow * D_ + sgc;
    const unsigned short* vS = Vp + (size_t)srow * N_ + sgc;
    const int aOff = wv * 512;

#define ATTN_STAGE(buf, kt)                                                  \
    {                                                                        \
        gl16(kS + (kt) * (64 * D_), &pool[(buf) * 4096 + aOff]);             \
        gl16(vS + (kt) * 64,        &pool[8192 + (buf) * 4096 + aOff]);      \
    }

    // --- hoisted inner LDS read offsets (loop-invariant) ---
    const int koff0 = (quad ^ (l15 & 7)) * 8;
    const int koff1 = ((4 + quad) ^ (l15 & 7)) * 8;
    const int vs128 = ((wk * 4 + quad) ^ (l15 & 7)) * 8;
    int kOff0[2], kOff1[2], vOff[4];
#pragma unroll
    for (int kb = 0; kb < 2; ++kb) {
        const int krow = (wk * 32 + kb * 16 + l15) * 64;
        kOff0[kb] = krow + koff0;
        kOff1[kb] = krow + koff1;
    }
#pragma unroll
    for (int nt = 0; nt < 4; ++nt)
        vOff[nt] = (nt * 16 + l15) * 64 + vs128;

    // bf16 1.0 x8 for the l = P.1 MFMA (K=32)
    short8 ones8;
#pragma unroll
    for (int i = 0; i < 8; ++i) ones8[i] = (short)0x3F80;

    f32x4 O[2][4];   // [q-subtile][nt] partial over this wave's 32 keys
#pragma unroll
    for (int s = 0; s < 2; ++s)
#pragma unroll
        for (int nt = 0; nt < 4; ++nt) O[s][nt] = (f32x4){0.f, 0.f, 0.f, 0.f};
    f32x4 Lacc[2] = {{0.f, 0.f, 0.f, 0.f}, {0.f, 0.f, 0.f, 0.f}};

    ATTN_STAGE(0, 0);

    for (int kt = 0; kt < 32; ++kt) {
        const int cur = kt & 1;
        __syncthreads();
        if (kt < 31) ATTN_STAGE(cur ^ 1, kt + 1);

        const unsigned short* Kc = pool + cur * 4096;
        const unsigned short* Vc = pool + 8192 + cur * 4096;

        // S^T per key-group kb (16 keys) x q-subtile s
        f32x4 st[2][2];
#pragma unroll
        for (int kb = 0; kb < 2; ++kb) {
            const short8 kf0 = *(const short8*)&Kc[kOff0[kb]];
            const short8 kf1 = *(const short8*)&Kc[kOff1[kb]];
#pragma unroll
            for (int s = 0; s < 2; ++s) {
                st[kb][s] = (f32x4){0.f, 0.f, 0.f, 0.f};
                st[kb][s] = MFMA16(kf0, qf[s][0], st[kb][s]);
                st[kb][s] = MFMA16(kf1, qf[s][1], st[kb][s]);
            }
        }

        // softmax numerator: p = exp2(s), packed straight into the K=32
        // A-operand slot order (= r14 VT slot order kappa).
        short8 pa8[2];
#pragma unroll
        for (int s = 0; s < 2; ++s) {
            uint4v u;
            u.x = pack_bf16_2(fast_exp2(st[0][s][0]), fast_exp2(st[0][s][1]));
            u.y = pack_bf16_2(fast_exp2(st[0][s][2]), fast_exp2(st[0][s][3]));
            u.z = pack_bf16_2(fast_exp2(st[1][s][0]), fast_exp2(st[1][s][1]));
            u.w = pack_bf16_2(fast_exp2(st[1][s][2]), fast_exp2(st[1][s][3]));
            pa8[s] = __builtin_bit_cast(short8, u);
        }

        // prioritize this wave through the pure-MFMA stretch (T5)
        __builtin_amdgcn_s_setprio(1);

        // l partials via MFMA (K=32): Lacc[s] += P[s] . 1
#pragma unroll
        for (int s = 0; s < 2; ++s)
            Lacc[s] = MFMA16(pa8[s], ones8, Lacc[s]);

        // PV (K=32): O[s][nt] += P[s] . V(all 32 keys of this wave)
#pragma unroll
        for (int nt = 0; nt < 4; ++nt) {
            const short8 v8 = *(const short8*)&Vc[vOff[nt]];
#pragma unroll
            for (int s = 0; s < 2; ++s)
                O[s][nt] = MFMA16(pa8[s], v8, O[s][nt]);
        }

        __builtin_amdgcn_s_setprio(0);
    }
#undef ATTN_STAGE

    // Lacc D-layout: row q_local = quad*4+g, all 16 cols identical -> lane
    // l15==0 of each quad publishes its 4 q rows.
    if (l15 == 0) {
#pragma unroll
        for (int s = 0; s < 2; ++s)
#pragma unroll
            for (int g = 0; g < 4; ++g)
                lsumBuf[wk][wq * 32 + s * 16 + quad * 4 + g] = Lacc[s][g];
    }
    __syncthreads();   // tile reads done (pool reusable) + lsumBuf visible

    // O D-layout: q = quad*4+g (row), d = nt*16 + l15 (col)
    float* red = (float*)pool;   // 8192 floats = 32KB; [wq][qsub 0..31][d]
    if (wk == 1) {
#pragma unroll
        for (int s = 0; s < 2; ++s)
#pragma unroll
            for (int nt = 0; nt < 4; ++nt)
#pragma unroll
                for (int g = 0; g < 4; ++g)
                    red[wq * 2048 + (s * 16 + quad * 4 + g) * 64 + nt * 16 + l15] =
                        O[s][nt][g];
    }
    __syncthreads();

    if (wk == 0) {
        const int b = bh >> 4, h = bh & 15;
#pragma unroll
        for (int s = 0; s < 2; ++s) {
            float inv[4];
#pragma unroll
            for (int g = 0; g < 4; ++g) {
                const int q = wq * 32 + s * 16 + quad * 4 + g;
                inv[g] = 1.0f / (lsumBuf[0][q] + lsumBuf[1][q]);
            }
#pragma unroll
            for (int nt = 0; nt < 4; ++nt) {
#pragma unroll
                for (int g = 0; g < 4; ++g) {
                    const float o = O[s][nt][g] +
                        red[wq * 2048 + (s * 16 + quad * 4 + g) * 64 + nt * 16 + l15];
                    const int qrow = qt * 128 + wq * 32 + s * 16 + quad * 4 + g;
                    CTX[((size_t)b * N_ + qrow) * E_ + h * D_ + nt * 16 + l15] =
                        f2bf(o * inv[g]);
                }
            }
        }
    }
}

// ---------------------------------------------------------------------------
// Kernel 3: out = ctx @ w_proj^T + b_proj.  128(M) x 64(N) tiles -> 512
// blocks = 2/CU.  C^T orientation -> float4 stores.
// r13: XCD-aware block swizzle (T1), 512 = 8*64 bijective.
// r17: staging bases + fragment offsets hoisted.
// r19: BK=64 via paired 32-wide half-buffers (16 iters, bit-exact).
// ---------------------------------------------------------------------------
__global__ __launch_bounds__(256) void proj_kernel(
    const unsigned short* __restrict__ A, const unsigned short* __restrict__ Bm,
    const float* __restrict__ bias, float* __restrict__ out)
{
    __shared__ __attribute__((aligned(16))) unsigned short As[2][2][128 * 32];
    __shared__ __attribute__((aligned(16))) unsigned short Bs[2][2][64 * 32];
    const int t    = threadIdx.x;
    const int wv   = t >> 6, lane = t & 63;
    const int quad = lane >> 4, l15 = lane & 15;
    const int wr   = wv & 1, wc = wv >> 1;
    const int lid  = blockIdx.x + 16 * blockIdx.y;       // 0..511
    const int swz  = (lid & 7) * 64 + (lid >> 3);        // bijective (512=8*64)
    const int bx   = swz & 15, by = swz >> 4;
    const int bm   = by * 128;   // ctx rows
    const int bn   = bx * 64;    // out cols

    f32x4 acc[2][4];
#pragma unroll
    for (int i = 0; i < 2; ++i)
#pragma unroll
        for (int j = 0; j < 4; ++j) acc[i][j] = (f32x4){0.f, 0.f, 0.f, 0.f};

    // --- r17 hoisted staging bases ---
    const int pc0 = wv * 128 + lane, pr0 = pc0 >> 2;
    const int pg0 = ((pc0 & 3) ^ ((pr0 >> 1) & 3)) * 8;
    const int pc1 = pc0 + 64, pr1 = pc1 >> 2;
    const int pg1 = ((pc1 & 3) ^ ((pr1 >> 1) & 3)) * 8;
    const int pcB = wv * 64 + lane, prB = pcB >> 2;
    const int pgB = ((pcB & 3) ^ ((prB >> 1) & 3)) * 8;
    const unsigned short* aS0 = A  + (size_t)(bm + pr0) * E_ + pg0;
    const unsigned short* aS1 = A  + (size_t)(bm + pr1) * E_ + pg1;
    const unsigned short* bS  = Bm + (size_t)(bn + prB) * E_ + pgB;
    const int ldsA0 = wv * 1024, ldsA1 = wv * 1024 + 512, ldsB0 = wv * 512;

// r19: stage BOTH 32-wide halves of K-pair it2 (K cols [it2*64, it2*64+64))
#define PROJ_STAGE(buf, it2)                                                 \
    {                                                                        \
        gl16(aS0 + (it2) * 64,      &As[buf][0][ldsA0]);                     \
        gl16(aS1 + (it2) * 64,      &As[buf][0][ldsA1]);                     \
        gl16(bS  + (it2) * 64,      &Bs[buf][0][ldsB0]);                     \
        gl16(aS0 + (it2) * 64 + 32, &As[buf][1][ldsA0]);                     \
        gl16(aS1 + (it2) * 64 + 32, &As[buf][1][ldsA1]);                     \
        gl16(bS  + (it2) * 64 + 32, &Bs[buf][1][ldsB0]);                     \
    }

    // --- r17 hoisted fragment offsets ---
    const int sw = (l15 >> 1) & 3;
    int offPM[2], offPN[4];
#pragma unroll
    for (int i = 0; i < 2; ++i)
        offPM[i] = (wr * 32 + i * 16 + l15) * 32 + ((quad ^ sw) * 8);
#pragma unroll
    for (int j = 0; j < 4; ++j)
        offPN[j] = (wc * 64 + j * 16 + l15) * 32 + ((quad ^ sw) * 8);

    PROJ_STAGE(0, 0);
    for (int it = 0; it < 16; ++it) {
        const int cur = it & 1;
        __syncthreads();
        if (it < 15) PROJ_STAGE(cur ^ 1, it + 1);
#pragma unroll
        for (int h = 0; h < 2; ++h) {
            short8 af[2], bf[4];
#pragma unroll
            for (int i = 0; i < 2; ++i)
                af[i] = *(const short8*)&Bs[cur][h][offPM[i]];
#pragma unroll
            for (int j = 0; j < 4; ++j)
                bf[j] = *(const short8*)&As[cur][h][offPN[j]];
#pragma unroll
            for (int i = 0; i < 2; ++i)
#pragma unroll
                for (int j = 0; j < 4; ++j)
                    acc[i][j] = MFMA16(af[i], bf[j], acc[i][j]);  // D[m=col][n=row]
        }
    }
#undef PROJ_STAGE

#pragma unroll
    for (int i = 0; i < 2; ++i) {
        const int col0 = bn + wr * 32 + i * 16 + quad * 4;
        const float4 bp = *(const float4*)(bias + col0);
#pragma unroll
        for (int j = 0; j < 4; ++j) {
            const int row = bm + wc * 64 + j * 16 + l15;
            float4 o;
            o.x = acc[i][j][0] + bp.x;
            o.y = acc[i][j][1] + bp.y;
            o.z = acc[i][j][2] + bp.z;
            o.w = acc[i][j][3] + bp.w;
            *(float4*)(out + (size_t)row * E_ + col0) = o;
        }
    }
}

// ---------------------------------------------------------------------------
extern "C" void kernel_launch(void* const* d_in, const int* in_sizes, int n_in,
                              void* d_out, int out_size, void* d_ws, size_t ws_size,
                              hipStream_t stream)
{
    const float* x      = (const float*)d_in[0];
    const float* w_qkv  = (const float*)d_in[1];
    const float* b_qkv  = (const float*)d_in[2];
    const float* w_proj = (const float*)d_in[3];
    const float* b_proj = (const float*)d_in[4];
    float* out = (float*)d_out;

    // ws (bf16 elems): xb 4M | wqp 3M | wpb 1M | Q 4M | K 4M | VT 4M | CTX 4M
    // then bias_perm (3072 fp32)
    unsigned short* xb  = (unsigned short*)d_ws;
    unsigned short* wqp = xb  + 4194304;
    unsigned short* wpb = wqp + 3145728;
    unsigned short* Q   = wpb + 1048576;
    unsigned short* K   = Q   + 4194304;
    unsigned short* VT  = K   + 4194304;
    unsigned short* CTX = VT  + 4194304;
    float* bias_perm    = (float*)(CTX + 4194304);

    dim3 blk(256);
    convert_kernel<<<dim3(4097), blk, 0, stream>>>(
        x, w_qkv, w_proj, b_qkv, xb, wqp, wpb, bias_perm);

    qkv_kernel<<<dim3(24, 32), blk, 0, stream>>>(xb, wqp, bias_perm, Q, K, VT);

    attn_kernel<<<dim3(B_ * H_ * (N_ / 128)), dim3(512), 0, stream>>>(Q, K, VT, CTX);

    proj_kernel<<<dim3(16, 32), blk, 0, stream>>>(CTX, wpb, b_proj, out);
}

// Round 15
// 175.737 us; speedup vs baseline: 1.1051x; 1.0103x over previous
//
#include <hip/hip_runtime.h>
#include <hip/hip_bf16.h>
#include <math.h>

#define B_   2
#define N_   2048
#define E_   1024
#define H_   16
#define D_   64
#define E3_  3072
#define M_   (B_ * N_)   // 4096

// log2(e)/8 folded into Q so softmax inner loop is a bare exp2
#define QSCALE 0.18033688011112042f

using short8  = __attribute__((ext_vector_type(8))) short;
using short4v = __attribute__((ext_vector_type(4))) short;
using f32x4   = __attribute__((ext_vector_type(4))) float;
using uint2v  = __attribute__((ext_vector_type(2))) unsigned int;
using uint4v  = __attribute__((ext_vector_type(4))) unsigned int;

#define MFMA16(a, b, c)    __builtin_amdgcn_mfma_f32_16x16x32_bf16((a), (b), (c), 0, 0, 0)

__device__ __forceinline__ unsigned short f2bf(float f) {
    __hip_bfloat16 h = __float2bfloat16(f);
    return __builtin_bit_cast(unsigned short, h);
}

__device__ __forceinline__ float fast_exp2(float x) {
#if __has_builtin(__builtin_amdgcn_exp2f)
    return __builtin_amdgcn_exp2f(x);
#else
    return exp2f(x);
#endif
}

// pack two floats to a bf16x2 dword.  gfx950 has v_cvt_pk_bf16_f32 (1 op,
// RNE); fallback = round-half-up bit trick (3 ops).
__device__ __forceinline__ unsigned int pack_bf16_2(float lo, float hi) {
#if __has_builtin(__builtin_amdgcn_cvt_pk_bf16_f32)
    auto pk = __builtin_amdgcn_cvt_pk_bf16_f32(lo, hi);
    return *(const unsigned int*)&pk;
#else
    unsigned int ulo = __builtin_bit_cast(unsigned int, lo) + 0x8000u;
    unsigned int uhi = __builtin_bit_cast(unsigned int, hi) + 0x8000u;
#if __has_builtin(__builtin_amdgcn_perm)
    return __builtin_amdgcn_perm(uhi, ulo, 0x07060302u);
#else
    return (uhi & 0xFFFF0000u) | (ulo >> 16);
#endif
#endif
}

// async global->LDS, 16B per lane
__device__ __forceinline__ void gl16(const void* g, void* l) {
    __builtin_amdgcn_global_load_lds(
        (__attribute__((address_space(1))) const void*)g,
        (__attribute__((address_space(3))) void*)l, 16, 0, 0);
}

// ---------------------------------------------------------------------------
// Kernel 0: fp32->bf16: x->xb; w_qkv row-permuted (slot s = c*1024+h*64+d) ->
// wqp; w_proj->wpb.  Block 4096: permuted (+Q-prescaled) bias -> bias_perm.
// ---------------------------------------------------------------------------
__global__ __launch_bounds__(256) void convert_kernel(
    const float* __restrict__ x, const float* __restrict__ wq,
    const float* __restrict__ wp, const float* __restrict__ b_qkv,
    unsigned short* __restrict__ xb, unsigned short* __restrict__ wqp,
    unsigned short* __restrict__ wpb, float* __restrict__ bias_perm)
{
    if (blockIdx.x == 4096) {
        for (int q = threadIdx.x; q < E3_; q += 256) {
            const int c = q >> 10, rem = q & 1023;
            const int h = rem >> 6, d = rem & 63;
            float v = b_qkv[h * 192 + d * 3 + c];
            if (c == 0) v *= QSCALE;
            bias_perm[q] = v;
        }
        return;
    }
    const int o = (blockIdx.x * 256 + threadIdx.x) * 8;
    const float* src;
    unsigned short* dst;
    if (o < 4194304) {                     // x: 4M
        src = x + o; dst = xb + o;
    } else if (o < 7340032) {              // w_qkv permuted: 3M
        const int oo = o - 4194304;
        const int s = oo >> 10, k = oo & 1023;
        const int c = s >> 10, rem = s & 1023;
        const int h = rem >> 6, d = rem & 63;
        src = wq + (size_t)(h * 192 + d * 3 + c) * E_ + k;
        dst = wqp + oo;
    } else {                               // w_proj: 1M
        const int oo = o - 7340032;
        src = wp + oo; dst = wpb + oo;
    }
    float4 a = *(const float4*)src;
    float4 b = *(const float4*)(src + 4);
    uint2v p0, p1;
    p0.x = pack_bf16_2(a.x, a.y); p0.y = pack_bf16_2(a.z, a.w);
    p1.x = pack_bf16_2(b.x, b.y); p1.y = pack_bf16_2(b.z, b.w);
    *(uint2v*)dst = p0;
    *(uint2v*)(dst + 4) = p1;
}

#define GEMM_PROLOG                                                          \
    const int t    = threadIdx.x;                                            \
    const int wv   = t >> 6, lane = t & 63;                                  \
    const int quad = lane >> 4, l15 = lane & 15;                             \
    const int wr   = wv & 1, wc = wv >> 1;                                   \
    f32x4 acc[4][4];                                                         \
    _Pragma("unroll")                                                        \
    for (int i = 0; i < 4; ++i)                                              \
        _Pragma("unroll")                                                    \
        for (int j = 0; j < 4; ++j) acc[i][j] = (f32x4){0.f, 0.f, 0.f, 0.f};

// counted-vmcnt barrier (R13-verified protocol): wait for all but the
// newest `n` of THIS wave's VMEM ops, then raw-barrier.  sched_barrier
// pins the following stage below the barrier.
#define PIPE_BARRIER(n)                                                      \
    {                                                                        \
        asm volatile("s_waitcnt vmcnt(" #n ")" ::: "memory");                \
        __builtin_amdgcn_s_barrier();                                        \
        __builtin_amdgcn_sched_barrier(0);                                   \
    }

// ---------------------------------------------------------------------------
// Kernel 1: merged qkv GEMM over all 3072 output slots (grid 24 x 32).
// 128x128 tile, BK=32, 4 waves (2x2), global_load_lds(16B), XOR-swizzled
// LDS.
// r22 (R13-verified, -15%): 3-BUFFER counted-vmcnt pipeline (48 KB LDS),
// depth-2 prefetch with vmcnt(4), keeping 3 blocks/CU.
// r13: XCD swizzle (768 = 8*96 bijective).  r14: VT key-paired store.
// r17: hoisted staging bases + fragment offsets.
// ---------------------------------------------------------------------------
__global__ __launch_bounds__(256) void qkv_kernel(
    const unsigned short* __restrict__ A, const unsigned short* __restrict__ Bm,
    const float* __restrict__ bias_perm,
    unsigned short* __restrict__ Q, unsigned short* __restrict__ K,
    unsigned short* __restrict__ VT)
{
    __shared__ __attribute__((aligned(16))) unsigned short As[3][128 * 32];
    __shared__ __attribute__((aligned(16))) unsigned short Bs[3][128 * 32];
    GEMM_PROLOG
    // XCD swizzle: HW round-robins original linear id across 8 XCDs.
    const int lid = blockIdx.x + 24 * blockIdx.y;        // 0..767
    const int swz = (lid & 7) * 96 + (lid >> 3);         // bijective (768=8*96)
    const int bx  = swz % 24, by = swz / 24;
    const int bm = by * 128;   // token rows
    const int bn = bx * 128;   // s slots
    const int c  = bn >> 10;   // 0=Q,1=K,2=V (uniform per block)

    // --- r17 hoisted staging bases ---
    const int chunk0 = wv * 128 + lane;
    const int row0   = chunk0 >> 2;
    const int g0     = ((chunk0 & 3) ^ ((row0 >> 1) & 3)) * 8;
    const int chunk1 = chunk0 + 64;
    const int row1   = chunk1 >> 2;
    const int g1     = ((chunk1 & 3) ^ ((row1 >> 1) & 3)) * 8;
    const unsigned short* aS0 = A  + (size_t)(bm + row0) * E_ + g0;
    const unsigned short* aS1 = A  + (size_t)(bm + row1) * E_ + g1;
    const unsigned short* bS0 = Bm + (size_t)(bn + row0) * E_ + g0;
    const unsigned short* bS1 = Bm + (size_t)(bn + row1) * E_ + g1;
    const int ldsOff0 = wv * 1024;        // shorts: (wv*128+ 0)*8
    const int ldsOff1 = wv * 1024 + 512;  // shorts: (wv*128+64)*8

#define QKV_STAGE(buf, k0)                                                   \
    {                                                                        \
        gl16(aS0 + (k0), &As[buf][ldsOff0]);                                 \
        gl16(bS0 + (k0), &Bs[buf][ldsOff0]);                                 \
        gl16(aS1 + (k0), &As[buf][ldsOff1]);                                 \
        gl16(bS1 + (k0), &Bs[buf][ldsOff1]);                                 \
    }

    // --- r17 hoisted fragment offsets (loop-invariant) ---
    const int sw = (l15 >> 1) & 3;
    int offM[4], offN[4];
#pragma unroll
    for (int i = 0; i < 4; ++i) {
        offM[i] = (wr * 64 + i * 16 + l15) * 32 + ((quad ^ sw) * 8);
        offN[i] = (wc * 64 + i * 16 + l15) * 32 + ((quad ^ sw) * 8);
    }

    QKV_STAGE(0, 0);
    QKV_STAGE(1, 32);
    int cur = 0, nx2 = 2;   // buf of it, buf of it+2 (rotating mod 3)
    if (c < 2) {
        for (int it = 0; it < 32; ++it) {
            if (it < 31) PIPE_BARRIER(4) else PIPE_BARRIER(0);
            if (it < 30) QKV_STAGE(nx2, (it + 2) * 32);
            short8 af[4], bf[4];
#pragma unroll
            for (int i = 0; i < 4; ++i) {
                af[i] = *(const short8*)&Bs[cur][offM[i]];   // m = s slots
                bf[i] = *(const short8*)&As[cur][offN[i]];   // n = tokens
            }
#pragma unroll
            for (int i = 0; i < 4; ++i)
#pragma unroll
                for (int j = 0; j < 4; ++j)
                    acc[i][j] = MFMA16(af[i], bf[j], acc[i][j]);  // D[m=s][n=tok]
            if (++cur == 3) cur = 0;
            if (++nx2 == 3) nx2 = 0;
        }
        const float scale = (c == 0) ? QSCALE : 1.0f;
        unsigned short* dst0 = (c == 0) ? Q : K;
#pragma unroll
        for (int i = 0; i < 4; ++i) {
            const int s0 = bn + wr * 64 + i * 16 + quad * 4;
            const int h  = (s0 >> 6) & 15;
            const int d0 = s0 & 63;
            const float4 bq = *(const float4*)(bias_perm + s0);
#pragma unroll
            for (int j = 0; j < 4; ++j) {
                const int row = bm + wc * 64 + j * 16 + l15;
                const int b   = row >> 11, n = row & (N_ - 1);
                const float v0 = fmaf(acc[i][j][0], scale, bq.x);
                const float v1 = fmaf(acc[i][j][1], scale, bq.y);
                const float v2 = fmaf(acc[i][j][2], scale, bq.z);
                const float v3 = fmaf(acc[i][j][3], scale, bq.w);
                uint2v pk;
                pk.x = pack_bf16_2(v0, v1);
                pk.y = pack_bf16_2(v2, v3);
                *(uint2v*)(dst0 + (((size_t)b * H_ + h) * N_ + n) * D_ + d0) = pk;
            }
        }
    } else {
        for (int it = 0; it < 32; ++it) {
            if (it < 31) PIPE_BARRIER(4) else PIPE_BARRIER(0);
            if (it < 30) QKV_STAGE(nx2, (it + 2) * 32);
            short8 af[4], bf[4];
#pragma unroll
            for (int i = 0; i < 4; ++i) {
                af[i] = *(const short8*)&As[cur][offM[i]];   // m = tokens
                bf[i] = *(const short8*)&Bs[cur][offN[i]];   // n = s slots
            }
#pragma unroll
            for (int i = 0; i < 4; ++i)
#pragma unroll
                for (int j = 0; j < 4; ++j)
                    acc[i][j] = MFMA16(af[i], bf[j], acc[i][j]);  // D[m=tok][n=s]
            if (++cur == 3) cur = 0;
            if (++nx2 == 3) nx2 = 0;
        }
#pragma unroll
        for (int j = 0; j < 4; ++j) {
            const int s = bn + wc * 64 + j * 16 + l15;
            const int h = (s >> 6) & 15, d = s & 63;
            const float bv = bias_perm[s];
#pragma unroll
            for (int i = 0; i < 4; ++i) {
                const int row0v = bm + wr * 64 + i * 16 + quad * 4;
                const int b     = row0v >> 11, n0 = row0v & (N_ - 1);
                // r14 key-pair permutation (bijective on 4-aligned groups):
                // np = (n0 & ~31) | gi*8 + hi*4, gi = (n0>>2)&3, hi = (n0>>4)&1
                const int np = (n0 & ~31) | ((((n0 >> 2) & 3) << 3) + (((n0 >> 4) & 1) << 2));
                uint2v pk;
                pk.x = pack_bf16_2(acc[i][j][0] + bv, acc[i][j][1] + bv);
                pk.y = pack_bf16_2(acc[i][j][2] + bv, acc[i][j][3] + bv);
                *(uint2v*)(VT + (((size_t)b * H_ + h) * D_ + d) * N_ + np) = pk;
            }
        }
    }
#undef QKV_STAGE
}

// ---------------------------------------------------------------------------
// Kernel 2: flash attention.
// r21: QBLK=128, 8 waves (512 thr), hybrid partition wq∈0..3, wk∈0..1 —
// per-wave kt body instruction-identical to the verified r15 kernel.
// r23: r22-protocol counted-vmcnt pipeline — 3 K-buffers + 3 V-buffers
// (48 KB pool), depth-2 prefetch, vmcnt(2) (each stage = 2 gl16/thread).
// Race proof (mirrors r22): stage(kt+2) writes buf[(kt+2)%3] =
// buf[(kt-1)%3]; every wave's ds_reads of that buffer completed before its
// barrier_kt arrival (lgkmcnt -> MFMA -> barrier in program order), and
// gl16s issue only after barrier release.  vmcnt(2): newest outstanding at
// the wait is stage(kt+1)'s 2 loads -> stage(kt) guaranteed landed.
// LDS 49 KB x 2 blocks/CU = 98 KB <= 160 (grid asks 2/CU; no occupancy
// change).  red epilogue (32 KB) fits the 48 KB pool.
// Grid 512 = 8*64 bijective XCD swizzle.  r20 setprio kept.  PV/lsum at
// K=32 (r15), hoisted addressing (r17).
// ---------------------------------------------------------------------------
__global__ __launch_bounds__(512, 4) void attn_kernel(
    const unsigned short* __restrict__ Q, const unsigned short* __restrict__ K,
    const unsigned short* __restrict__ VT, unsigned short* __restrict__ CTX)
{
    __shared__ __attribute__((aligned(16))) unsigned short pool[24576]; // Ks[3]|Vs[3]
    __shared__ float lsumBuf[2][128];   // [wk][q]

    const int t    = threadIdx.x;
    const int wv   = t >> 6, lane = t & 63;
    const int quad = lane >> 4, l15 = lane & 15;
    const int wq   = wv & 3, wk = wv >> 2;
    // XCD-aware bijective remap (512 = 8*64)
    const int lid  = blockIdx.x;
    const int swzb = (lid & 7) * 64 + (lid >> 3);
    const int qt   = swzb & 15;   // N/128 q-tiles
    const int bh   = swzb >> 4;

    const unsigned short* Kp = K + (size_t)bh * N_ * D_;
    const unsigned short* Vp = VT + (size_t)bh * D_ * N_;

    // Q B-frags for this wave's 2 q-subtiles (q rows qt*128 + wq*32 + s*16)
    short8 qf[2][2];
#pragma unroll
    for (int s = 0; s < 2; ++s) {
        const unsigned short* Qp =
            Q + ((size_t)bh * N_ + qt * 128 + (wq * 2 + s) * 16 + l15) * D_;
        qf[s][0] = *(const short8*)(Qp + quad * 8);
        qf[s][1] = *(const short8*)(Qp + 32 + quad * 8);
    }

    // --- staging bases: 512 threads, one 16B chunk each (cch = t) ---
    const int srow = t >> 3;
    const int sgc  = ((t & 7) ^ (srow & 7)) * 8;
    const unsigned short* kS = Kp + (size_t)srow * D_ + sgc;
    const unsigned short* vS = Vp + (size_t)srow * N_ + sgc;
    const int aOff = wv * 512;

#define ATTN_STAGE(buf, kt)                                                  \
    {                                                                        \
        gl16(kS + (kt) * (64 * D_), &pool[(buf) * 4096 + aOff]);             \
        gl16(vS + (kt) * 64,        &pool[12288 + (buf) * 4096 + aOff]);     \
    }

    // --- hoisted inner LDS read offsets (loop-invariant) ---
    const int koff0 = (quad ^ (l15 & 7)) * 8;
    const int koff1 = ((4 + quad) ^ (l15 & 7)) * 8;
    const int vs128 = ((wk * 4 + quad) ^ (l15 & 7)) * 8;
    int kOff0[2], kOff1[2], vOff[4];
#pragma unroll
    for (int kb = 0; kb < 2; ++kb) {
        const int krow = (wk * 32 + kb * 16 + l15) * 64;
        kOff0[kb] = krow + koff0;
        kOff1[kb] = krow + koff1;
    }
#pragma unroll
    for (int nt = 0; nt < 4; ++nt)
        vOff[nt] = (nt * 16 + l15) * 64 + vs128;

    // bf16 1.0 x8 for the l = P.1 MFMA (K=32)
    short8 ones8;
#pragma unroll
    for (int i = 0; i < 8; ++i) ones8[i] = (short)0x3F80;

    f32x4 O[2][4];   // [q-subtile][nt] partial over this wave's 32 keys
#pragma unroll
    for (int s = 0; s < 2; ++s)
#pragma unroll
        for (int nt = 0; nt < 4; ++nt) O[s][nt] = (f32x4){0.f, 0.f, 0.f, 0.f};
    f32x4 Lacc[2] = {{0.f, 0.f, 0.f, 0.f}, {0.f, 0.f, 0.f, 0.f}};

    ATTN_STAGE(0, 0);
    ATTN_STAGE(1, 1);
    int cur = 0, nx2 = 2;   // buf of kt, buf of kt+2 (rotating mod 3)

    for (int kt = 0; kt < 32; ++kt) {
        if (kt < 31) PIPE_BARRIER(2) else PIPE_BARRIER(0);
        if (kt < 30) ATTN_STAGE(nx2, kt + 2);

        const unsigned short* Kc = pool + cur * 4096;
        const unsigned short* Vc = pool + 12288 + cur * 4096;

        // S^T per key-group kb (16 keys) x q-subtile s
        f32x4 st[2][2];
#pragma unroll
        for (int kb = 0; kb < 2; ++kb) {
            const short8 kf0 = *(const short8*)&Kc[kOff0[kb]];
            const short8 kf1 = *(const short8*)&Kc[kOff1[kb]];
#pragma unroll
            for (int s = 0; s < 2; ++s) {
                st[kb][s] = (f32x4){0.f, 0.f, 0.f, 0.f};
                st[kb][s] = MFMA16(kf0, qf[s][0], st[kb][s]);
                st[kb][s] = MFMA16(kf1, qf[s][1], st[kb][s]);
            }
        }

        // softmax numerator: p = exp2(s), packed straight into the K=32
        // A-operand slot order (= r14 VT slot order kappa).
        short8 pa8[2];
#pragma unroll
        for (int s = 0; s < 2; ++s) {
            uint4v u;
            u.x = pack_bf16_2(fast_exp2(st[0][s][0]), fast_exp2(st[0][s][1]));
            u.y = pack_bf16_2(fast_exp2(st[0][s][2]), fast_exp2(st[0][s][3]));
            u.z = pack_bf16_2(fast_exp2(st[1][s][0]), fast_exp2(st[1][s][1]));
            u.w = pack_bf16_2(fast_exp2(st[1][s][2]), fast_exp2(st[1][s][3]));
            pa8[s] = __builtin_bit_cast(short8, u);
        }

        // prioritize this wave through the pure-MFMA stretch (T5)
        __builtin_amdgcn_s_setprio(1);

        // l partials via MFMA (K=32): Lacc[s] += P[s] . 1
#pragma unroll
        for (int s = 0; s < 2; ++s)
            Lacc[s] = MFMA16(pa8[s], ones8, Lacc[s]);

        // PV (K=32): O[s][nt] += P[s] . V(all 32 keys of this wave)
#pragma unroll
        for (int nt = 0; nt < 4; ++nt) {
            const short8 v8 = *(const short8*)&Vc[vOff[nt]];
#pragma unroll
            for (int s = 0; s < 2; ++s)
                O[s][nt] = MFMA16(pa8[s], v8, O[s][nt]);
        }

        __builtin_amdgcn_s_setprio(0);

        if (++cur == 3) cur = 0;
        if (++nx2 == 3) nx2 = 0;
    }
#undef ATTN_STAGE

    // Lacc D-layout: row q_local = quad*4+g, all 16 cols identical -> lane
    // l15==0 of each quad publishes its 4 q rows.
    if (l15 == 0) {
#pragma unroll
        for (int s = 0; s < 2; ++s)
#pragma unroll
            for (int g = 0; g < 4; ++g)
                lsumBuf[wk][wq * 32 + s * 16 + quad * 4 + g] = Lacc[s][g];
    }
    __syncthreads();   // tile reads done (pool reusable) + lsumBuf visible

    // O D-layout: q = quad*4+g (row), d = nt*16 + l15 (col)
    float* red = (float*)pool;   // 8192 floats = 32KB; [wq][qsub 0..31][d]
    if (wk == 1) {
#pragma unroll
        for (int s = 0; s < 2; ++s)
#pragma unroll
            for (int nt = 0; nt < 4; ++nt)
#pragma unroll
                for (int g = 0; g < 4; ++g)
                    red[wq * 2048 + (s * 16 + quad * 4 + g) * 64 + nt * 16 + l15] =
                        O[s][nt][g];
    }
    __syncthreads();

    if (wk == 0) {
        const int b = bh >> 4, h = bh & 15;
#pragma unroll
        for (int s = 0; s < 2; ++s) {
            float inv[4];
#pragma unroll
            for (int g = 0; g < 4; ++g) {
                const int q = wq * 32 + s * 16 + quad * 4 + g;
                inv[g] = 1.0f / (lsumBuf[0][q] + lsumBuf[1][q]);
            }
#pragma unroll
            for (int nt = 0; nt < 4; ++nt) {
#pragma unroll
                for (int g = 0; g < 4; ++g) {
                    const float o = O[s][nt][g] +
                        red[wq * 2048 + (s * 16 + quad * 4 + g) * 64 + nt * 16 + l15];
                    const int qrow = qt * 128 + wq * 32 + s * 16 + quad * 4 + g;
                    CTX[((size_t)b * N_ + qrow) * E_ + h * D_ + nt * 16 + l15] =
                        f2bf(o * inv[g]);
                }
            }
        }
    }
}

// ---------------------------------------------------------------------------
// Kernel 3: out = ctx @ w_proj^T + b_proj.  128(M) x 64(N) tiles -> 512
// blocks = 2/CU.  C^T orientation -> float4 stores.
// r13: XCD-aware block swizzle (T1), 512 = 8*64 bijective.
// r17: staging bases + fragment offsets hoisted.
// r19: BK=64 via paired 32-wide half-buffers (16 iters, bit-exact).
// r23: r22-protocol counted-vmcnt pipeline — 3 buffers (72 KB LDS),
// depth-2 prefetch, vmcnt(6) (each stage = 6 gl16/thread).  2 blocks/CU
// needs 144 KB <= 160 -> no occupancy change.  Same race proof as r22.
// ---------------------------------------------------------------------------
__global__ __launch_bounds__(256) void proj_kernel(
    const unsigned short* __restrict__ A, const unsigned short* __restrict__ Bm,
    const float* __restrict__ bias, float* __restrict__ out)
{
    __shared__ __attribute__((aligned(16))) unsigned short As[3][2][128 * 32];
    __shared__ __attribute__((aligned(16))) unsigned short Bs[3][2][64 * 32];
    const int t    = threadIdx.x;
    const int wv   = t >> 6, lane = t & 63;
    const int quad = lane >> 4, l15 = lane & 15;
    const int wr   = wv & 1, wc = wv >> 1;
    const int lid  = blockIdx.x + 16 * blockIdx.y;       // 0..511
    const int swz  = (lid & 7) * 64 + (lid >> 3);        // bijective (512=8*64)
    const int bx   = swz & 15, by = swz >> 4;
    const int bm   = by * 128;   // ctx rows
    const int bn   = bx * 64;    // out cols

    f32x4 acc[2][4];
#pragma unroll
    for (int i = 0; i < 2; ++i)
#pragma unroll
        for (int j = 0; j < 4; ++j) acc[i][j] = (f32x4){0.f, 0.f, 0.f, 0.f};

    // --- r17 hoisted staging bases ---
    const int pc0 = wv * 128 + lane, pr0 = pc0 >> 2;
    const int pg0 = ((pc0 & 3) ^ ((pr0 >> 1) & 3)) * 8;
    const int pc1 = pc0 + 64, pr1 = pc1 >> 2;
    const int pg1 = ((pc1 & 3) ^ ((pr1 >> 1) & 3)) * 8;
    const int pcB = wv * 64 + lane, prB = pcB >> 2;
    const int pgB = ((pcB & 3) ^ ((prB >> 1) & 3)) * 8;
    const unsigned short* aS0 = A  + (size_t)(bm + pr0) * E_ + pg0;
    const unsigned short* aS1 = A  + (size_t)(bm + pr1) * E_ + pg1;
    const unsigned short* bS  = Bm + (size_t)(bn + prB) * E_ + pgB;
    const int ldsA0 = wv * 1024, ldsA1 = wv * 1024 + 512, ldsB0 = wv * 512;

// r19: stage BOTH 32-wide halves of K-pair it2 (K cols [it2*64, it2*64+64))
#define PROJ_STAGE(buf, it2)                                                 \
    {                                                                        \
        gl16(aS0 + (it2) * 64,      &As[buf][0][ldsA0]);                     \
        gl16(aS1 + (it2) * 64,      &As[buf][0][ldsA1]);                     \
        gl16(bS  + (it2) * 64,      &Bs[buf][0][ldsB0]);                     \
        gl16(aS0 + (it2) * 64 + 32, &As[buf][1][ldsA0]);                     \
        gl16(aS1 + (it2) * 64 + 32, &As[buf][1][ldsA1]);                     \
        gl16(bS  + (it2) * 64 + 32, &Bs[buf][1][ldsB0]);                     \
    }

    // --- r17 hoisted fragment offsets ---
    const int sw = (l15 >> 1) & 3;
    int offPM[2], offPN[4];
#pragma unroll
    for (int i = 0; i < 2; ++i)
        offPM[i] = (wr * 32 + i * 16 + l15) * 32 + ((quad ^ sw) * 8);
#pragma unroll
    for (int j = 0; j < 4; ++j)
        offPN[j] = (wc * 64 + j * 16 + l15) * 32 + ((quad ^ sw) * 8);

    PROJ_STAGE(0, 0);
    PROJ_STAGE(1, 1);
    int cur = 0, nx2 = 2;   // buf of it, buf of it+2 (rotating mod 3)
    for (int it = 0; it < 16; ++it) {
        if (it < 15) PIPE_BARRIER(6) else PIPE_BARRIER(0);
        if (it < 14) PROJ_STAGE(nx2, it + 2);
#pragma unroll
        for (int h = 0; h < 2; ++h) {
            short8 af[2], bf[4];
#pragma unroll
            for (int i = 0; i < 2; ++i)
                af[i] = *(const short8*)&Bs[cur][h][offPM[i]];
#pragma unroll
            for (int j = 0; j < 4; ++j)
                bf[j] = *(const short8*)&As[cur][h][offPN[j]];
#pragma unroll
            for (int i = 0; i < 2; ++i)
#pragma unroll
                for (int j = 0; j < 4; ++j)
                    acc[i][j] = MFMA16(af[i], bf[j], acc[i][j]);  // D[m=col][n=row]
        }
        if (++cur == 3) cur = 0;
        if (++nx2 == 3) nx2 = 0;
    }
#undef PROJ_STAGE

#pragma unroll
    for (int i = 0; i < 2; ++i) {
        const int col0 = bn + wr * 32 + i * 16 + quad * 4;
        const float4 bp = *(const float4*)(bias + col0);
#pragma unroll
        for (int j = 0; j < 4; ++j) {
            const int row = bm + wc * 64 + j * 16 + l15;
            float4 o;
            o.x = acc[i][j][0] + bp.x;
            o.y = acc[i][j][1] + bp.y;
            o.z = acc[i][j][2] + bp.z;
            o.w = acc[i][j][3] + bp.w;
            *(float4*)(out + (size_t)row * E_ + col0) = o;
        }
    }
}

// ---------------------------------------------------------------------------
extern "C" void kernel_launch(void* const* d_in, const int* in_sizes, int n_in,
                              void* d_out, int out_size, void* d_ws, size_t ws_size,
                              hipStream_t stream)
{
    const float* x      = (const float*)d_in[0];
    const float* w_qkv  = (const float*)d_in[1];
    const float* b_qkv  = (const float*)d_in[2];
    const float* w_proj = (const float*)d_in[3];
    const float* b_proj = (const float*)d_in[4];
    float* out = (float*)d_out;

    // ws (bf16 elems): xb 4M | wqp 3M | wpb 1M | Q 4M | K 4M | VT 4M | CTX 4M
    // then bias_perm (3072 fp32)
    unsigned short* xb  = (unsigned short*)d_ws;
    unsigned short* wqp = xb  + 4194304;
    unsigned short* wpb = wqp + 3145728;
    unsigned short* Q   = wpb + 1048576;
    unsigned short* K   = Q   + 4194304;
    unsigned short* VT  = K   + 4194304;
    unsigned short* CTX = VT  + 4194304;
    float* bias_perm    = (float*)(CTX + 4194304);

    dim3 blk(256);
    convert_kernel<<<dim3(4097), blk, 0, stream>>>(
        x, w_qkv, w_proj, b_qkv, xb, wqp, wpb, bias_perm);

    qkv_kernel<<<dim3(24, 32), blk, 0, stream>>>(xb, wqp, bias_perm, Q, K, VT);

    attn_kernel<<<dim3(B_ * H_ * (N_ / 128)), dim3(512), 0, stream>>>(Q, K, VT, CTX);

    proj_kernel<<<dim3(16, 32), blk, 0, stream>>>(CTX, wpb, b_proj, out);
}